// Round 13
// baseline (404.063 us; speedup 1.0000x reference)
//
#include <hip/hip_runtime.h>

#define N_NODES  50000
#define N_PAD    50048
#define N_EDGES  800000
#define N_GRAPHS 2000
#define N_PAIRS  4096
#define IN_CH    64
#define EMB      128
#define HID      256
#define PPB      16
#define WIN      2048
#define NWIN     25    // 25*2048 = 51200 >= N_NODES

// ---------------- custom zero-fill ----------------
__global__ void k_zero(float4* __restrict__ p, int n4) {
    int i = blockIdx.x * 256 + threadIdx.x;
    if (i < n4) p[i] = make_float4(0.f, 0.f, 0.f, 0.f);
}

// ---------------- hist pass: windowed LDS histogram (no global atomics for deg/pos_e) ----------------
// blocks 0..24: node-window histogram -> deg + pos_e ; blocks 25,26: cnt ; blocks 27+: transposes
__global__ __launch_bounds__(1024) void k_hist(
        const int* __restrict__ col, const int* __restrict__ batch,
        const float* __restrict__ w1, const float* __restrict__ w2,
        int* __restrict__ deg, int* __restrict__ pos_e, int* __restrict__ cnt,
        float* __restrict__ wt1, float* __restrict__ wt2) {
    int b = blockIdx.x, t = threadIdx.x;
    if (b < NWIN) {
        __shared__ int hist[WIN];
        int base = b * WIN;
        for (int j = t; j < WIN; j += 1024) hist[j] = 0;
        __syncthreads();
        int i = t;
        #pragma unroll 1
        for (int k = 0; k < 195; ++k, i += 4096) {
            int c0 = col[i + 0];
            int c1 = col[i + 1024];
            int c2 = col[i + 2048];
            int c3 = col[i + 3072];
            int l0 = c0 - base, l1 = c1 - base, l2 = c2 - base, l3 = c3 - base;
            if ((unsigned)l0 < (unsigned)WIN) pos_e[i + 0]    = atomicAdd(&hist[l0], 1);
            if ((unsigned)l1 < (unsigned)WIN) pos_e[i + 1024] = atomicAdd(&hist[l1], 1);
            if ((unsigned)l2 < (unsigned)WIN) pos_e[i + 2048] = atomicAdd(&hist[l2], 1);
            if ((unsigned)l3 < (unsigned)WIN) pos_e[i + 3072] = atomicAdd(&hist[l3], 1);
        }
        for (; i < N_EDGES; i += 1024) {       // tail (798720..799999)
            int c = col[i];
            int l = c - base;
            if ((unsigned)l < (unsigned)WIN) pos_e[i] = atomicAdd(&hist[l], 1);
        }
        __syncthreads();
        for (int j = t; j < WIN; j += 1024) {
            int n = base + j;
            if (n < N_NODES) deg[n] = hist[j];
        }
    } else if (b < NWIN + 2) {
        for (int i = (b - NWIN) * 1024 + t; i < N_NODES; i += 2048)
            atomicAdd(&cnt[batch[i]], 1);
    } else {
        for (int i = (b - NWIN - 2) * 1024 + t; i < EMB * IN_CH + EMB * EMB; i += 4096) {
            if (i < EMB * IN_CH) {
                int j = i / IN_CH, k = i % IN_CH;
                wt1[k * EMB + j] = w1[i];
            } else {
                int q = i - EMB * IN_CH;
                int j = q / EMB, k = q % EMB;
                wt2[k * EMB + j] = w2[q];
            }
        }
    }
}

// ---------------- multi-block exclusive scan ----------------
__device__ inline int wave_incl_scan(int x, int lane) {
    #pragma unroll
    for (int off = 1; off < 64; off <<= 1) {
        int y = __shfl_up(x, off, 64);
        if (lane >= off) x += y;
    }
    return x;
}

__global__ void k_scan1(const int* __restrict__ in, int* __restrict__ part, int n) {
    __shared__ int ws[4];
    int i = blockIdx.x * 256 + threadIdx.x;
    int lane = threadIdx.x & 63, wid = threadIdx.x >> 6;
    int v = (i < n) ? in[i] : 0;
    int x = wave_incl_scan(v, lane);
    if (lane == 63) ws[wid] = x;
    __syncthreads();
    if (threadIdx.x == 0) part[blockIdx.x] = ws[0] + ws[1] + ws[2] + ws[3];
}

// block 0: exclusive scan of part[nb]; block 1: digitize(dd)->rankx
__global__ void k_scan2d(int* __restrict__ part, int nb,
                         const int* __restrict__ dd, int* __restrict__ rankx) {
    int t = threadIdx.x, lane = t & 63, wid = t >> 6;
    if (blockIdx.x == 0) {
        __shared__ int ws[4];
        int v = (t < nb) ? part[t] : 0;
        int x = wave_incl_scan(v, lane);
        if (lane == 63) ws[wid] = x;
        __syncthreads();
        int add = 0;
        for (int w = 0; w < wid; ++w) add += ws[w];
        if (t < nb) part[t] = x - v + add;   // exclusive
    } else {
        __shared__ int pres[N_GRAPHS];
        __shared__ int ws2[4];
        __shared__ int carry;
        for (int i = t; i < N_GRAPHS; i += 256) pres[i] = 0;
        __syncthreads();
        for (int i = t; i < 2 * N_PAIRS; i += 256) pres[dd[i]] = 1;
        if (t == 0) carry = 0;
        __syncthreads();
        for (int base = 0; base < N_GRAPHS; base += 256) {
            int i = base + t;
            int v = (i < N_GRAPHS) ? pres[i] : 0;
            int x = wave_incl_scan(v, lane);
            if (lane == 63) ws2[wid] = x;
            __syncthreads();
            int add = carry;
            for (int w = 0; w < wid; ++w) add += ws2[w];
            if (i < N_GRAPHS) rankx[i] = x - v + add;
            __syncthreads();
            if (t == 255) carry = add + x;
            __syncthreads();
        }
    }
}

// scan3 + dinv + off sentinel fused
__global__ void k_scan3d(const int* __restrict__ in, const int* __restrict__ part,
                         int* __restrict__ off, float* __restrict__ dinv) {
    __shared__ int ws[4];
    int i = blockIdx.x * 256 + threadIdx.x;
    int lane = threadIdx.x & 63, wid = threadIdx.x >> 6;
    int v = (i < N_NODES) ? in[i] : 0;
    int x = wave_incl_scan(v, lane);
    if (lane == 63) ws[wid] = x;
    __syncthreads();
    int add = part[blockIdx.x];
    for (int w = 0; w < wid; ++w) add += ws[w];
    if (i < N_NODES) {
        off[i] = x - v + add;
        dinv[i] = 1.0f / sqrtf((float)(v + 1));   // +1 self loop
    }
    if (i == 0) off[N_NODES] = N_EDGES;
}

// ---------------- CSR fill (atomic-free) + xs = x*dinv scale, one kernel ----------------
__global__ void k_fill_scale(const int* __restrict__ row, const int* __restrict__ col,
                             const int* __restrict__ pos_e, const int* __restrict__ off,
                             int* __restrict__ csr_row,
                             const float4* __restrict__ x, const float* __restrict__ dinv,
                             float4* __restrict__ xs) {
    int idx = blockIdx.x * 256 + threadIdx.x;
    if (idx < N_EDGES) {
        int c = col[idx];
        int p = pos_e[idx];
        csr_row[off[c] + p] = row[idx];
    } else {
        int i = idx - N_EDGES;           // exactly N_NODES*16 of these
        int n = i >> 4;
        float d = dinv[n];
        float4 v = x[i];
        v.x *= d; v.y *= d; v.z *= d; v.w *= d;
        xs[i] = v;
    }
}

__device__ inline void f4add(float4& a, const float4 b) {
    a.x += b.x; a.y += b.y; a.z += b.z; a.w += b.w;
}

// ---------------- pull aggregation (unroll 8): out[n] = dinv[n]*(sum hs[r] + hs[n]) ----------------
template <int C>
__global__ void k_gather8(const float4* __restrict__ hs, const int* __restrict__ csr_row,
                          const int* __restrict__ off, const float* __restrict__ dinv,
                          float4* __restrict__ out) {
    constexpr int L = C / 4;
    constexpr int NPB = 256 / L;
    int local = threadIdx.x / L;
    int c4 = threadIdx.x % L;
    int n = blockIdx.x * NPB + local;
    int s = off[n], e = off[n + 1];
    float4 acc = hs[n * L + c4];      // self term
    int i = s;
    for (; i + 8 <= e; i += 8) {
        int r0 = csr_row[i + 0], r1 = csr_row[i + 1], r2 = csr_row[i + 2], r3 = csr_row[i + 3];
        int r4 = csr_row[i + 4], r5 = csr_row[i + 5], r6 = csr_row[i + 6], r7 = csr_row[i + 7];
        float4 a0 = hs[r0 * L + c4], a1 = hs[r1 * L + c4];
        float4 a2 = hs[r2 * L + c4], a3 = hs[r3 * L + c4];
        float4 a4 = hs[r4 * L + c4], a5 = hs[r5 * L + c4];
        float4 a6 = hs[r6 * L + c4], a7 = hs[r7 * L + c4];
        f4add(a0, a1); f4add(a2, a3); f4add(a4, a5); f4add(a6, a7);
        f4add(a0, a2); f4add(a4, a6);
        f4add(a0, a4);
        f4add(acc, a0);
    }
    for (; i < e; ++i) {
        int r = csr_row[i];
        float4 a = hs[r * L + c4];
        f4add(acc, a);
    }
    float dn = dinv[n];
    acc.x *= dn; acc.y *= dn; acc.z *= dn; acc.w *= dn;
    out[n * L + c4] = acc;
}

// ---------------- GEMM v5: A-tile staged in LDS (contiguous), barrier-free k-loop ----------------
template <int K, bool RELU, bool BIAS, bool POSTSCALE>
__global__ void k_gemmv5(const float* __restrict__ A, const float* __restrict__ Wt,
                         const float* __restrict__ bias, const float* __restrict__ rowscale,
                         float* __restrict__ out) {
    __shared__ __align__(16) float a_lds[64 * K];
    int t = threadIdx.x;
    {
        const float4* Ag = reinterpret_cast<const float4*>(A + (size_t)blockIdx.x * 64 * K);
        float4* Al = reinterpret_cast<float4*>(a_lds);
        constexpr int NV = (64 * K) / (4 * 256);
        #pragma unroll
        for (int i = 0; i < NV; ++i) Al[t + i * 256] = Ag[t + i * 256];
    }
    __syncthreads();
    int cq = (t & 31) << 2;
    int rg = t >> 5;
    float4 acc[8];
    #pragma unroll
    for (int r = 0; r < 8; ++r) acc[r] = make_float4(0.f, 0.f, 0.f, 0.f);
    #pragma unroll 2
    for (int k = 0; k < K; k += 4) {
        float4 w0 = *reinterpret_cast<const float4*>(&Wt[(k + 0) * EMB + cq]);
        float4 w1 = *reinterpret_cast<const float4*>(&Wt[(k + 1) * EMB + cq]);
        float4 w2 = *reinterpret_cast<const float4*>(&Wt[(k + 2) * EMB + cq]);
        float4 w3 = *reinterpret_cast<const float4*>(&Wt[(k + 3) * EMB + cq]);
        #pragma unroll
        for (int r = 0; r < 8; ++r) {
            float4 a = *reinterpret_cast<const float4*>(&a_lds[(rg * 8 + r) * K + k]);
            acc[r].x = fmaf(a.x, w0.x, fmaf(a.y, w1.x, fmaf(a.z, w2.x, fmaf(a.w, w3.x, acc[r].x))));
            acc[r].y = fmaf(a.x, w0.y, fmaf(a.y, w1.y, fmaf(a.z, w2.y, fmaf(a.w, w3.y, acc[r].y))));
            acc[r].z = fmaf(a.x, w0.z, fmaf(a.y, w1.z, fmaf(a.z, w2.z, fmaf(a.w, w3.z, acc[r].z))));
            acc[r].w = fmaf(a.x, w0.w, fmaf(a.y, w1.w, fmaf(a.z, w2.w, fmaf(a.w, w3.w, acc[r].w))));
        }
    }
    int row0 = blockIdx.x * 64 + rg * 8;
    #pragma unroll
    for (int r = 0; r < 8; ++r) {
        int row = row0 + r;
        if (row < N_NODES) {
            float4 v = acc[r];
            if (BIAS) {
                float4 b = *reinterpret_cast<const float4*>(&bias[cq]);
                v.x += b.x; v.y += b.y; v.z += b.z; v.w += b.w;
            }
            if (RELU) {
                v.x = fmaxf(v.x, 0.f); v.y = fmaxf(v.y, 0.f);
                v.z = fmaxf(v.z, 0.f); v.w = fmaxf(v.w, 0.f);
            }
            if (POSTSCALE) {
                float sc = rowscale[row];
                v.x *= sc; v.y *= sc; v.z *= sc; v.w *= sc;
            }
            *reinterpret_cast<float4*>(&out[(size_t)row * EMB + cq]) = v;
        }
    }
}

// ---------------- conv2 gather half-pass: 256B rows from t2, + bias/relu/dinv + run-based readout ----------------
template <int HALF>
__global__ void k_gro_h(const float4* __restrict__ t2, const int* __restrict__ csr_row,
                        const int* __restrict__ off, const float* __restrict__ dinv,
                        const float* __restrict__ bias, const int* __restrict__ batch,
                        float* __restrict__ gsum) {
    constexpr int NPB = 16;
    __shared__ __align__(16) float hb[NPB][64];
    __shared__ int bg[NPB];
    int t = threadIdx.x;
    int local = t >> 4;               // 0..15
    int c4 = t & 15;                  // float4 lane within the 64-ch half
    int n0 = blockIdx.x * NPB;
    int n = n0 + local;
    if (t < NPB) bg[t] = batch[n0 + t];
    int s = off[n], e = off[n + 1];
    const int cidx = HALF * 16 + c4;
    float4 acc = t2[(size_t)n * 32 + cidx];      // self term
    int i = s;
    for (; i + 8 <= e; i += 8) {
        int r0 = csr_row[i + 0], r1 = csr_row[i + 1], r2 = csr_row[i + 2], r3 = csr_row[i + 3];
        int r4 = csr_row[i + 4], r5 = csr_row[i + 5], r6 = csr_row[i + 6], r7 = csr_row[i + 7];
        float4 a0 = t2[(size_t)r0 * 32 + cidx], a1 = t2[(size_t)r1 * 32 + cidx];
        float4 a2 = t2[(size_t)r2 * 32 + cidx], a3 = t2[(size_t)r3 * 32 + cidx];
        float4 a4 = t2[(size_t)r4 * 32 + cidx], a5 = t2[(size_t)r5 * 32 + cidx];
        float4 a6 = t2[(size_t)r6 * 32 + cidx], a7 = t2[(size_t)r7 * 32 + cidx];
        f4add(a0, a1); f4add(a2, a3); f4add(a4, a5); f4add(a6, a7);
        f4add(a0, a2); f4add(a4, a6);
        f4add(a0, a4);
        f4add(acc, a0);
    }
    for (; i < e; ++i) {
        float4 a = t2[(size_t)csr_row[i] * 32 + cidx];
        f4add(acc, a);
    }
    float dn = dinv[n];
    float4 b = reinterpret_cast<const float4*>(bias)[cidx];
    acc.x = fmaxf(fmaf(acc.x, dn, b.x), 0.f);
    acc.y = fmaxf(fmaf(acc.y, dn, b.y), 0.f);
    acc.z = fmaxf(fmaf(acc.z, dn, b.z), 0.f);
    acc.w = fmaxf(fmaf(acc.w, dn, b.w), 0.f);
    *reinterpret_cast<float4*>(&hb[local][c4 * 4]) = acc;
    __syncthreads();
    {   // readout: ch = t&63 within half, quarter q scans 4 rows
        int ch = t & 63, q = t >> 6;
        int j0 = q * 4;
        int g = bg[j0];
        float a = 0.f;
        #pragma unroll
        for (int j = j0; j < j0 + 4; ++j) {
            int gj = bg[j];
            if (gj != g) { atomicAdd(&gsum[g * EMB + HALF * 64 + ch], a); a = 0.f; g = gj; }
            a += hb[j][ch];
        }
        atomicAdd(&gsum[g * EMB + HALF * 64 + ch], a);
    }
}

// ---------------- pair MLP, 16 pairs/block, mean-division fused at load ----------------
__global__ void k_mlp16(const float* __restrict__ gemb, const int* __restrict__ cnt,
                        const int* __restrict__ dd, const int* __restrict__ rankx,
                        const float* __restrict__ w1, const float* __restrict__ b1,
                        const float* __restrict__ w2, const float* __restrict__ b2,
                        float* __restrict__ out) {
    __shared__ __align__(16) float pv[PPB][2 * EMB];
    __shared__ float wpart[4][PPB];
    int p0 = blockIdx.x * PPB;
    int t = threadIdx.x;             // 0..255
    int lane = t & 63, wid = t >> 6;
    #pragma unroll
    for (int j = 0; j < PPB; ++j) {
        int p = p0 + j;
        if (t < EMB) {
            int ga = rankx[dd[p]];
            int ca = cnt[ga];
            float ra = 1.0f / (float)(ca > 1 ? ca : 1);
            pv[j][t] = gemb[ga * EMB + t] * ra;
        } else {
            int gb = rankx[dd[N_PAIRS + p]];
            int cb = cnt[gb];
            float rb = 1.0f / (float)(cb > 1 ? cb : 1);
            pv[j][t] = gemb[gb * EMB + (t - EMB)] * rb;
        }
    }
    __syncthreads();
    float acc[PPB];
    float bv = b1[t];
    #pragma unroll
    for (int j = 0; j < PPB; ++j) acc[j] = bv;
    const float4* wrow = reinterpret_cast<const float4*>(&w1[t * 2 * EMB]);
    for (int k = 0; k < (2 * EMB) / 4; ++k) {
        float4 w = wrow[k];
        #pragma unroll
        for (int j = 0; j < PPB; ++j) {
            const float4 xv = *reinterpret_cast<const float4*>(&pv[j][k * 4]);
            acc[j] = fmaf(xv.x, w.x, fmaf(xv.y, w.y, fmaf(xv.z, w.z, fmaf(xv.w, w.w, acc[j]))));
        }
    }
    float w2t = w2[t];
    float contrib[PPB];
    #pragma unroll
    for (int j = 0; j < PPB; ++j) contrib[j] = fmaxf(acc[j], 0.f) * w2t;
    #pragma unroll
    for (int off = 32; off > 0; off >>= 1) {
        #pragma unroll
        for (int j = 0; j < PPB; ++j) contrib[j] += __shfl_down(contrib[j], off, 64);
    }
    if (lane == 0) {
        #pragma unroll
        for (int j = 0; j < PPB; ++j) wpart[wid][j] = contrib[j];
    }
    __syncthreads();
    if (t < PPB) {
        out[p0 + t] = wpart[0][t] + wpart[1][t] + wpart[2][t] + wpart[3][t] + b2[0];
    }
}

extern "C" void kernel_launch(void* const* d_in, const int* in_sizes, int n_in,
                              void* d_out, int out_size, void* d_ws, size_t ws_size,
                              hipStream_t stream) {
    const float* x        = (const float*)d_in[0];
    const int*   ei       = (const int*)d_in[1];      // [2, E]
    const int*   batch    = (const int*)d_in[2];
    const int*   dd       = (const int*)d_in[3];      // [2, P]
    const float* conv1_w  = (const float*)d_in[4];
    const float* conv1_b  = (const float*)d_in[5];
    const float* conv2_w  = (const float*)d_in[6];
    const float* conv2_b  = (const float*)d_in[7];
    const float* reg1_w   = (const float*)d_in[8];
    const float* reg1_b   = (const float*)d_in[9];
    const float* reg2_w   = (const float*)d_in[10];
    const float* reg2_b   = (const float*)d_in[11];
    float* outp = (float*)d_out;

    const int* ei_row = ei;
    const int* ei_col = ei + N_EDGES;

    // ---- workspace layout ----
    char* ws = (char*)d_ws;
    size_t o = 0;
    auto alloc = [&](size_t bytes) -> void* {
        void* p = ws + o;
        o = (o + bytes + 255) & ~(size_t)255;
        return p;
    };
    size_t zero_start = o;
    int*   cnt     = (int*)alloc(N_GRAPHS * 4);
    float* gsum    = (float*)alloc(N_GRAPHS * EMB * 4);
    size_t zero_bytes = o - zero_start;
    int*   deg     = (int*)alloc(N_NODES * 4);        // fully written by k_hist (no zeroing)
    int*   off     = (int*)alloc((N_NODES + 1) * 4);
    float* dinv    = (float*)alloc(N_NODES * 4);
    int*   part    = (int*)alloc(256 * 4);
    int*   pos_e   = (int*)alloc(N_EDGES * 4);
    int*   csr_row = (int*)alloc(N_EDGES * 4);
    int*   rankx   = (int*)alloc(N_GRAPHS * 4);
    float* Wt1     = (float*)alloc(IN_CH * EMB * 4);
    float* Wt2     = (float*)alloc(EMB * EMB * 4);
    float* aggx    = (float*)alloc((size_t)N_PAD * IN_CH * 4);
    float* h1s     = (float*)alloc((size_t)N_PAD * EMB * 4);
    float* t2      = (float*)alloc((size_t)N_PAD * EMB * 4);
    float* xs      = t2;   // xs (12.8MB) dead before GEMM2 writes t2

    (void)ws_size; (void)in_sizes; (void)n_in; (void)out_size;

    // zero cnt+gsum (~1 MB)
    {
        int n4 = (int)(zero_bytes / 16);
        k_zero<<<(n4 + 255) / 256, 256, 0, stream>>>((float4*)(ws + zero_start), n4);
    }

    // hist: windowed LDS histogram -> deg,pos_e (no global atomics) + cnt + transposes
    k_hist<<<NWIN + 2 + 4, 1024, 0, stream>>>(ei_col, batch, conv1_w, conv2_w,
                                              deg, pos_e, cnt, Wt1, Wt2);
    {
        int nb = (N_NODES + 255) / 256;   // 196
        k_scan1<<<nb, 256, 0, stream>>>(deg, part, N_NODES);
        k_scan2d<<<2, 256, 0, stream>>>(part, nb, dd, rankx);   // + digitize in block 1
        k_scan3d<<<nb, 256, 0, stream>>>(deg, part, off, dinv);
    }
    k_fill_scale<<<(N_EDGES + N_NODES * (IN_CH / 4)) / 256, 256, 0, stream>>>(
        ei_row, ei_col, pos_e, off, csr_row, (const float4*)x, dinv, (float4*)xs);

    // conv1: aggregate in 64-dim input space, then GEMM (+bias,relu, x dinv postscale)
    k_gather8<IN_CH><<<N_NODES / (256 / (IN_CH / 4)), 256, 0, stream>>>(
        (const float4*)xs, csr_row, off, dinv, (float4*)aggx);
    k_gemmv5<IN_CH, true, true, true><<<N_PAD / 64, 256, 0, stream>>>(
        aggx, Wt1, conv1_b, dinv, h1s);

    // conv2: GEMM (LDS-A), then channel-split gather halves with fused bias/relu/readout
    k_gemmv5<EMB, false, false, false><<<N_PAD / 64, 256, 0, stream>>>(
        h1s, Wt2, nullptr, nullptr, t2);
    k_gro_h<0><<<N_NODES / 16, 256, 0, stream>>>(
        (const float4*)t2, csr_row, off, dinv, conv2_b, batch, gsum);
    k_gro_h<1><<<N_NODES / 16, 256, 0, stream>>>(
        (const float4*)t2, csr_row, off, dinv, conv2_b, batch, gsum);

    // pair MLP (mean division fused)
    k_mlp16<<<N_PAIRS / PPB, 256, 0, stream>>>(gsum, cnt, dd, rankx,
                                               reg1_w, reg1_b, reg2_w, reg2_b, outp);
}

// Round 14
// 387.306 us; speedup vs baseline: 1.0433x; 1.0433x over previous
//
#include <hip/hip_runtime.h>

#define N_NODES  50000
#define N_PAD    50048
#define N_EDGES  800000
#define N_GRAPHS 2000
#define N_PAIRS  4096
#define IN_CH    64
#define EMB      128
#define HID      256
#define PPB      16
#define WIN      2048
#define NWIN     25    // 25*2048 = 51200 >= N_NODES
#define NSEG     32
#define SEGSZ    (N_EDGES / NSEG)   // 25000

// ---------------- custom zero-fill ----------------
__global__ void k_zero(float4* __restrict__ p, int n4) {
    int i = blockIdx.x * 256 + threadIdx.x;
    if (i < n4) p[i] = make_float4(0.f, 0.f, 0.f, 0.f);
}

// ---------------- pass A: segmented windowed LDS histogram ----------------
// blocks 0..799: (segment s = b/NWIN, window w = b%NWIN) -> pos_loc + cnt_part
// blocks 800,801: cnt atomics ; blocks 802..805: weight transposes
__global__ __launch_bounds__(1024) void k_histA(
        const int* __restrict__ col, const int* __restrict__ batch,
        const float* __restrict__ w1, const float* __restrict__ w2,
        int* __restrict__ pos_loc, int* __restrict__ cnt_part, int* __restrict__ cnt,
        float* __restrict__ wt1, float* __restrict__ wt2) {
    int b = blockIdx.x, t = threadIdx.x;
    if (b < NWIN * NSEG) {
        int s = b / NWIN;             // same-segment blocks adjacent -> co-scheduled, L2 reuse
        int w = b % NWIN;
        __shared__ int hist[WIN];
        int base = w * WIN;
        for (int j = t; j < WIN; j += 1024) hist[j] = 0;
        __syncthreads();
        int e0 = s * SEGSZ;
        for (int i = t; i < SEGSZ; i += 1024) {
            int e = e0 + i;
            int c = col[e];
            int l = c - base;
            if ((unsigned)l < (unsigned)WIN) pos_loc[e] = atomicAdd(&hist[l], 1);
        }
        __syncthreads();
        for (int j = t; j < WIN; j += 1024)
            cnt_part[(w * NSEG + s) * WIN + j] = hist[j];
    } else if (b < NWIN * NSEG + 2) {
        for (int i = (b - NWIN * NSEG) * 1024 + t; i < N_NODES; i += 2048)
            atomicAdd(&cnt[batch[i]], 1);
    } else {
        for (int i = (b - NWIN * NSEG - 2) * 1024 + t; i < EMB * IN_CH + EMB * EMB; i += 4096) {
            if (i < EMB * IN_CH) {
                int j = i / IN_CH, k = i % IN_CH;
                wt1[k * EMB + j] = w1[i];
            } else {
                int q = i - EMB * IN_CH;
                int j = q / EMB, k = q % EMB;
                wt2[k * EMB + j] = w2[q];
            }
        }
    }
}

// ---------------- pass B: per-node exclusive scan over segments (in-place) + deg ----------------
__global__ void k_histB(int* __restrict__ cnt_part, int* __restrict__ deg) {
    int n = blockIdx.x * 256 + threadIdx.x;
    if (n >= NWIN * WIN) return;
    int w = n >> 11, j = n & (WIN - 1);
    int acc = 0;
    #pragma unroll 4
    for (int s = 0; s < NSEG; ++s) {
        int idx = (w * NSEG + s) * WIN + j;
        int v = cnt_part[idx];
        cnt_part[idx] = acc;         // exclusive segment base
        acc += v;
    }
    if (n < N_NODES) deg[n] = acc;
}

// ---------------- multi-block exclusive scan ----------------
__device__ inline int wave_incl_scan(int x, int lane) {
    #pragma unroll
    for (int off = 1; off < 64; off <<= 1) {
        int y = __shfl_up(x, off, 64);
        if (lane >= off) x += y;
    }
    return x;
}

__global__ void k_scan1(const int* __restrict__ in, int* __restrict__ part, int n) {
    __shared__ int ws[4];
    int i = blockIdx.x * 256 + threadIdx.x;
    int lane = threadIdx.x & 63, wid = threadIdx.x >> 6;
    int v = (i < n) ? in[i] : 0;
    int x = wave_incl_scan(v, lane);
    if (lane == 63) ws[wid] = x;
    __syncthreads();
    if (threadIdx.x == 0) part[blockIdx.x] = ws[0] + ws[1] + ws[2] + ws[3];
}

// block 0: exclusive scan of part[nb]; block 1: digitize(dd)->rankx
__global__ void k_scan2d(int* __restrict__ part, int nb,
                         const int* __restrict__ dd, int* __restrict__ rankx) {
    int t = threadIdx.x, lane = t & 63, wid = t >> 6;
    if (blockIdx.x == 0) {
        __shared__ int ws[4];
        int v = (t < nb) ? part[t] : 0;
        int x = wave_incl_scan(v, lane);
        if (lane == 63) ws[wid] = x;
        __syncthreads();
        int add = 0;
        for (int w = 0; w < wid; ++w) add += ws[w];
        if (t < nb) part[t] = x - v + add;   // exclusive
    } else {
        __shared__ int pres[N_GRAPHS];
        __shared__ int ws2[4];
        __shared__ int carry;
        for (int i = t; i < N_GRAPHS; i += 256) pres[i] = 0;
        __syncthreads();
        for (int i = t; i < 2 * N_PAIRS; i += 256) pres[dd[i]] = 1;
        if (t == 0) carry = 0;
        __syncthreads();
        for (int base = 0; base < N_GRAPHS; base += 256) {
            int i = base + t;
            int v = (i < N_GRAPHS) ? pres[i] : 0;
            int x = wave_incl_scan(v, lane);
            if (lane == 63) ws2[wid] = x;
            __syncthreads();
            int add = carry;
            for (int w = 0; w < wid; ++w) add += ws2[w];
            if (i < N_GRAPHS) rankx[i] = x - v + add;
            __syncthreads();
            if (t == 255) carry = add + x;
            __syncthreads();
        }
    }
}

// scan3 + dinv + off sentinel fused
__global__ void k_scan3d(const int* __restrict__ in, const int* __restrict__ part,
                         int* __restrict__ off, float* __restrict__ dinv) {
    __shared__ int ws[4];
    int i = blockIdx.x * 256 + threadIdx.x;
    int lane = threadIdx.x & 63, wid = threadIdx.x >> 6;
    int v = (i < N_NODES) ? in[i] : 0;
    int x = wave_incl_scan(v, lane);
    if (lane == 63) ws[wid] = x;
    __syncthreads();
    int add = part[blockIdx.x];
    for (int w = 0; w < wid; ++w) add += ws[w];
    if (i < N_NODES) {
        off[i] = x - v + add;
        dinv[i] = 1.0f / sqrtf((float)(v + 1));   // +1 self loop
    }
    if (i == 0) off[N_NODES] = N_EDGES;
}

// ---------------- CSR fill (atomic-free, segmented bases) + xs = x*dinv scale ----------------
__global__ void k_fill_scale(const int* __restrict__ row, const int* __restrict__ col,
                             const int* __restrict__ pos_loc, const int* __restrict__ cnt_part,
                             const int* __restrict__ off, int* __restrict__ csr_row,
                             const float4* __restrict__ x, const float* __restrict__ dinv,
                             float4* __restrict__ xs) {
    int idx = blockIdx.x * 256 + threadIdx.x;
    if (idx < N_EDGES) {
        int c = col[idx];
        int s = idx / SEGSZ;
        int p = pos_loc[idx] + cnt_part[((c >> 11) * NSEG + s) * WIN + (c & (WIN - 1))];
        csr_row[off[c] + p] = row[idx];
    } else {
        int i = idx - N_EDGES;           // exactly N_NODES*16 of these
        int n = i >> 4;
        float d = dinv[n];
        float4 v = x[i];
        v.x *= d; v.y *= d; v.z *= d; v.w *= d;
        xs[i] = v;
    }
}

__device__ inline void f4add(float4& a, const float4 b) {
    a.x += b.x; a.y += b.y; a.z += b.z; a.w += b.w;
}

// ---------------- pull aggregation (unroll 8): out[n] = dinv[n]*(sum hs[r] + hs[n]) ----------------
template <int C>
__global__ void k_gather8(const float4* __restrict__ hs, const int* __restrict__ csr_row,
                          const int* __restrict__ off, const float* __restrict__ dinv,
                          float4* __restrict__ out) {
    constexpr int L = C / 4;
    constexpr int NPB = 256 / L;
    int local = threadIdx.x / L;
    int c4 = threadIdx.x % L;
    int n = blockIdx.x * NPB + local;
    int s = off[n], e = off[n + 1];
    float4 acc = hs[n * L + c4];      // self term
    int i = s;
    for (; i + 8 <= e; i += 8) {
        int r0 = csr_row[i + 0], r1 = csr_row[i + 1], r2 = csr_row[i + 2], r3 = csr_row[i + 3];
        int r4 = csr_row[i + 4], r5 = csr_row[i + 5], r6 = csr_row[i + 6], r7 = csr_row[i + 7];
        float4 a0 = hs[r0 * L + c4], a1 = hs[r1 * L + c4];
        float4 a2 = hs[r2 * L + c4], a3 = hs[r3 * L + c4];
        float4 a4 = hs[r4 * L + c4], a5 = hs[r5 * L + c4];
        float4 a6 = hs[r6 * L + c4], a7 = hs[r7 * L + c4];
        f4add(a0, a1); f4add(a2, a3); f4add(a4, a5); f4add(a6, a7);
        f4add(a0, a2); f4add(a4, a6);
        f4add(a0, a4);
        f4add(acc, a0);
    }
    for (; i < e; ++i) {
        int r = csr_row[i];
        float4 a = hs[r * L + c4];
        f4add(acc, a);
    }
    float dn = dinv[n];
    acc.x *= dn; acc.y *= dn; acc.z *= dn; acc.w *= dn;
    out[n * L + c4] = acc;
}

// ---------------- GEMM v5: A-tile staged in LDS (contiguous), barrier-free k-loop ----------------
template <int K, bool RELU, bool BIAS, bool POSTSCALE>
__global__ void k_gemmv5(const float* __restrict__ A, const float* __restrict__ Wt,
                         const float* __restrict__ bias, const float* __restrict__ rowscale,
                         float* __restrict__ out) {
    __shared__ __align__(16) float a_lds[64 * K];
    int t = threadIdx.x;
    {
        const float4* Ag = reinterpret_cast<const float4*>(A + (size_t)blockIdx.x * 64 * K);
        float4* Al = reinterpret_cast<float4*>(a_lds);
        constexpr int NV = (64 * K) / (4 * 256);
        #pragma unroll
        for (int i = 0; i < NV; ++i) Al[t + i * 256] = Ag[t + i * 256];
    }
    __syncthreads();
    int cq = (t & 31) << 2;
    int rg = t >> 5;
    float4 acc[8];
    #pragma unroll
    for (int r = 0; r < 8; ++r) acc[r] = make_float4(0.f, 0.f, 0.f, 0.f);
    #pragma unroll 2
    for (int k = 0; k < K; k += 4) {
        float4 w0 = *reinterpret_cast<const float4*>(&Wt[(k + 0) * EMB + cq]);
        float4 w1 = *reinterpret_cast<const float4*>(&Wt[(k + 1) * EMB + cq]);
        float4 w2 = *reinterpret_cast<const float4*>(&Wt[(k + 2) * EMB + cq]);
        float4 w3 = *reinterpret_cast<const float4*>(&Wt[(k + 3) * EMB + cq]);
        #pragma unroll
        for (int r = 0; r < 8; ++r) {
            float4 a = *reinterpret_cast<const float4*>(&a_lds[(rg * 8 + r) * K + k]);
            acc[r].x = fmaf(a.x, w0.x, fmaf(a.y, w1.x, fmaf(a.z, w2.x, fmaf(a.w, w3.x, acc[r].x))));
            acc[r].y = fmaf(a.x, w0.y, fmaf(a.y, w1.y, fmaf(a.z, w2.y, fmaf(a.w, w3.y, acc[r].y))));
            acc[r].z = fmaf(a.x, w0.z, fmaf(a.y, w1.z, fmaf(a.z, w2.z, fmaf(a.w, w3.z, acc[r].z))));
            acc[r].w = fmaf(a.x, w0.w, fmaf(a.y, w1.w, fmaf(a.z, w2.w, fmaf(a.w, w3.w, acc[r].w))));
        }
    }
    int row0 = blockIdx.x * 64 + rg * 8;
    #pragma unroll
    for (int r = 0; r < 8; ++r) {
        int row = row0 + r;
        if (row < N_NODES) {
            float4 v = acc[r];
            if (BIAS) {
                float4 b = *reinterpret_cast<const float4*>(&bias[cq]);
                v.x += b.x; v.y += b.y; v.z += b.z; v.w += b.w;
            }
            if (RELU) {
                v.x = fmaxf(v.x, 0.f); v.y = fmaxf(v.y, 0.f);
                v.z = fmaxf(v.z, 0.f); v.w = fmaxf(v.w, 0.f);
            }
            if (POSTSCALE) {
                float sc = rowscale[row];
                v.x *= sc; v.y *= sc; v.z *= sc; v.w *= sc;
            }
            *reinterpret_cast<float4*>(&out[(size_t)row * EMB + cq]) = v;
        }
    }
}

// ---------------- conv2 gather half-pass: 256B rows from t2, + bias/relu/dinv + run-based readout ----------------
template <int HALF>
__global__ void k_gro_h(const float4* __restrict__ t2, const int* __restrict__ csr_row,
                        const int* __restrict__ off, const float* __restrict__ dinv,
                        const float* __restrict__ bias, const int* __restrict__ batch,
                        float* __restrict__ gsum) {
    constexpr int NPB = 16;
    __shared__ __align__(16) float hb[NPB][64];
    __shared__ int bg[NPB];
    int t = threadIdx.x;
    int local = t >> 4;               // 0..15
    int c4 = t & 15;                  // float4 lane within the 64-ch half
    int n0 = blockIdx.x * NPB;
    int n = n0 + local;
    if (t < NPB) bg[t] = batch[n0 + t];
    int s = off[n], e = off[n + 1];
    const int cidx = HALF * 16 + c4;
    float4 acc = t2[(size_t)n * 32 + cidx];      // self term
    int i = s;
    for (; i + 8 <= e; i += 8) {
        int r0 = csr_row[i + 0], r1 = csr_row[i + 1], r2 = csr_row[i + 2], r3 = csr_row[i + 3];
        int r4 = csr_row[i + 4], r5 = csr_row[i + 5], r6 = csr_row[i + 6], r7 = csr_row[i + 7];
        float4 a0 = t2[(size_t)r0 * 32 + cidx], a1 = t2[(size_t)r1 * 32 + cidx];
        float4 a2 = t2[(size_t)r2 * 32 + cidx], a3 = t2[(size_t)r3 * 32 + cidx];
        float4 a4 = t2[(size_t)r4 * 32 + cidx], a5 = t2[(size_t)r5 * 32 + cidx];
        float4 a6 = t2[(size_t)r6 * 32 + cidx], a7 = t2[(size_t)r7 * 32 + cidx];
        f4add(a0, a1); f4add(a2, a3); f4add(a4, a5); f4add(a6, a7);
        f4add(a0, a2); f4add(a4, a6);
        f4add(a0, a4);
        f4add(acc, a0);
    }
    for (; i < e; ++i) {
        float4 a = t2[(size_t)csr_row[i] * 32 + cidx];
        f4add(acc, a);
    }
    float dn = dinv[n];
    float4 b = reinterpret_cast<const float4*>(bias)[cidx];
    acc.x = fmaxf(fmaf(acc.x, dn, b.x), 0.f);
    acc.y = fmaxf(fmaf(acc.y, dn, b.y), 0.f);
    acc.z = fmaxf(fmaf(acc.z, dn, b.z), 0.f);
    acc.w = fmaxf(fmaf(acc.w, dn, b.w), 0.f);
    *reinterpret_cast<float4*>(&hb[local][c4 * 4]) = acc;
    __syncthreads();
    {   // readout: ch = t&63 within half, quarter q scans 4 rows
        int ch = t & 63, q = t >> 6;
        int j0 = q * 4;
        int g = bg[j0];
        float a = 0.f;
        #pragma unroll
        for (int j = j0; j < j0 + 4; ++j) {
            int gj = bg[j];
            if (gj != g) { atomicAdd(&gsum[g * EMB + HALF * 64 + ch], a); a = 0.f; g = gj; }
            a += hb[j][ch];
        }
        atomicAdd(&gsum[g * EMB + HALF * 64 + ch], a);
    }
}

// ---------------- pair MLP, 16 pairs/block, mean-division fused at load ----------------
__global__ void k_mlp16(const float* __restrict__ gemb, const int* __restrict__ cnt,
                        const int* __restrict__ dd, const int* __restrict__ rankx,
                        const float* __restrict__ w1, const float* __restrict__ b1,
                        const float* __restrict__ w2, const float* __restrict__ b2,
                        float* __restrict__ out) {
    __shared__ __align__(16) float pv[PPB][2 * EMB];
    __shared__ float wpart[4][PPB];
    int p0 = blockIdx.x * PPB;
    int t = threadIdx.x;             // 0..255
    int lane = t & 63, wid = t >> 6;
    #pragma unroll
    for (int j = 0; j < PPB; ++j) {
        int p = p0 + j;
        if (t < EMB) {
            int ga = rankx[dd[p]];
            int ca = cnt[ga];
            float ra = 1.0f / (float)(ca > 1 ? ca : 1);
            pv[j][t] = gemb[ga * EMB + t] * ra;
        } else {
            int gb = rankx[dd[N_PAIRS + p]];
            int cb = cnt[gb];
            float rb = 1.0f / (float)(cb > 1 ? cb : 1);
            pv[j][t] = gemb[gb * EMB + (t - EMB)] * rb;
        }
    }
    __syncthreads();
    float acc[PPB];
    float bv = b1[t];
    #pragma unroll
    for (int j = 0; j < PPB; ++j) acc[j] = bv;
    const float4* wrow = reinterpret_cast<const float4*>(&w1[t * 2 * EMB]);
    for (int k = 0; k < (2 * EMB) / 4; ++k) {
        float4 w = wrow[k];
        #pragma unroll
        for (int j = 0; j < PPB; ++j) {
            const float4 xv = *reinterpret_cast<const float4*>(&pv[j][k * 4]);
            acc[j] = fmaf(xv.x, w.x, fmaf(xv.y, w.y, fmaf(xv.z, w.z, fmaf(xv.w, w.w, acc[j]))));
        }
    }
    float w2t = w2[t];
    float contrib[PPB];
    #pragma unroll
    for (int j = 0; j < PPB; ++j) contrib[j] = fmaxf(acc[j], 0.f) * w2t;
    #pragma unroll
    for (int off = 32; off > 0; off >>= 1) {
        #pragma unroll
        for (int j = 0; j < PPB; ++j) contrib[j] += __shfl_down(contrib[j], off, 64);
    }
    if (lane == 0) {
        #pragma unroll
        for (int j = 0; j < PPB; ++j) wpart[wid][j] = contrib[j];
    }
    __syncthreads();
    if (t < PPB) {
        out[p0 + t] = wpart[0][t] + wpart[1][t] + wpart[2][t] + wpart[3][t] + b2[0];
    }
}

extern "C" void kernel_launch(void* const* d_in, const int* in_sizes, int n_in,
                              void* d_out, int out_size, void* d_ws, size_t ws_size,
                              hipStream_t stream) {
    const float* x        = (const float*)d_in[0];
    const int*   ei       = (const int*)d_in[1];      // [2, E]
    const int*   batch    = (const int*)d_in[2];
    const int*   dd       = (const int*)d_in[3];      // [2, P]
    const float* conv1_w  = (const float*)d_in[4];
    const float* conv1_b  = (const float*)d_in[5];
    const float* conv2_w  = (const float*)d_in[6];
    const float* conv2_b  = (const float*)d_in[7];
    const float* reg1_w   = (const float*)d_in[8];
    const float* reg1_b   = (const float*)d_in[9];
    const float* reg2_w   = (const float*)d_in[10];
    const float* reg2_b   = (const float*)d_in[11];
    float* outp = (float*)d_out;

    const int* ei_row = ei;
    const int* ei_col = ei + N_EDGES;

    // ---- workspace layout ----
    char* ws = (char*)d_ws;
    size_t o = 0;
    auto alloc = [&](size_t bytes) -> void* {
        void* p = ws + o;
        o = (o + bytes + 255) & ~(size_t)255;
        return p;
    };
    size_t zero_start = o;
    int*   cnt     = (int*)alloc(N_GRAPHS * 4);
    float* gsum    = (float*)alloc(N_GRAPHS * EMB * 4);
    size_t zero_bytes = o - zero_start;
    int*   deg     = (int*)alloc(N_NODES * 4);        // fully written by k_histB
    int*   off     = (int*)alloc((N_NODES + 1) * 4);
    float* dinv    = (float*)alloc(N_NODES * 4);
    int*   part    = (int*)alloc(256 * 4);
    int*   pos_loc = (int*)alloc(N_EDGES * 4);
    int*   cnt_part= (int*)alloc((size_t)NWIN * NSEG * WIN * 4);   // 6.55 MB
    int*   csr_row = (int*)alloc(N_EDGES * 4);
    int*   rankx   = (int*)alloc(N_GRAPHS * 4);
    float* Wt1     = (float*)alloc(IN_CH * EMB * 4);
    float* Wt2     = (float*)alloc(EMB * EMB * 4);
    float* aggx    = (float*)alloc((size_t)N_PAD * IN_CH * 4);
    float* h1s     = (float*)alloc((size_t)N_PAD * EMB * 4);
    float* t2      = (float*)alloc((size_t)N_PAD * EMB * 4);
    float* xs      = t2;   // xs (12.8MB) dead before GEMM2 writes t2

    (void)ws_size; (void)in_sizes; (void)n_in; (void)out_size;

    // zero cnt+gsum (~1 MB)
    {
        int n4 = (int)(zero_bytes / 16);
        k_zero<<<(n4 + 255) / 256, 256, 0, stream>>>((float4*)(ws + zero_start), n4);
    }

    // pass A: segmented windowed histogram (LDS atomics only) + cnt + transposes
    k_histA<<<NWIN * NSEG + 2 + 4, 1024, 0, stream>>>(ei_col, batch, conv1_w, conv2_w,
                                                      pos_loc, cnt_part, cnt, Wt1, Wt2);
    // pass B: per-node segment scan -> bases (in-place) + deg
    k_histB<<<(NWIN * WIN + 255) / 256, 256, 0, stream>>>(cnt_part, deg);
    {
        int nb = (N_NODES + 255) / 256;   // 196
        k_scan1<<<nb, 256, 0, stream>>>(deg, part, N_NODES);
        k_scan2d<<<2, 256, 0, stream>>>(part, nb, dd, rankx);   // + digitize in block 1
        k_scan3d<<<nb, 256, 0, stream>>>(deg, part, off, dinv);
    }
    k_fill_scale<<<(N_EDGES + N_NODES * (IN_CH / 4)) / 256, 256, 0, stream>>>(
        ei_row, ei_col, pos_loc, cnt_part, off, csr_row, (const float4*)x, dinv, (float4*)xs);

    // conv1: aggregate in 64-dim input space, then GEMM (+bias,relu, x dinv postscale)
    k_gather8<IN_CH><<<N_NODES / (256 / (IN_CH / 4)), 256, 0, stream>>>(
        (const float4*)xs, csr_row, off, dinv, (float4*)aggx);
    k_gemmv5<IN_CH, true, true, true><<<N_PAD / 64, 256, 0, stream>>>(
        aggx, Wt1, conv1_b, dinv, h1s);

    // conv2: GEMM (LDS-A), then channel-split gather halves with fused bias/relu/readout
    k_gemmv5<EMB, false, false, false><<<N_PAD / 64, 256, 0, stream>>>(
        h1s, Wt2, nullptr, nullptr, t2);
    k_gro_h<0><<<N_NODES / 16, 256, 0, stream>>>(
        (const float4*)t2, csr_row, off, dinv, conv2_b, batch, gsum);
    k_gro_h<1><<<N_NODES / 16, 256, 0, stream>>>(
        (const float4*)t2, csr_row, off, dinv, conv2_b, batch, gsum);

    // pair MLP (mean division fused)
    k_mlp16<<<N_PAIRS / PPB, 256, 0, stream>>>(gsum, cnt, dd, rankx,
                                               reg1_w, reg1_b, reg2_w, reg2_b, outp);
}

// Round 15
// 234.936 us; speedup vs baseline: 1.7199x; 1.6486x over previous
//
#include <hip/hip_runtime.h>

#define N_NODES  50000
#define N_PAD    50048
#define N_EDGES  800000
#define N_GRAPHS 2000
#define N_PAIRS  4096
#define IN_CH    64
#define EMB      128
#define HID      256
#define PPB      16
#define DPAD     16    // deg counter padding: one 64B line per counter

// ---------------- custom zero-fill ----------------
__global__ void k_zero(float4* __restrict__ p, int n4) {
    int i = blockIdx.x * 256 + threadIdx.x;
    if (i < n4) p[i] = make_float4(0.f, 0.f, 0.f, 0.f);
}

// ---------------- pre pass: in-degree (line-padded atomics) + per-edge rank + graph counts + transposes ----------------
__global__ void k_pre(const int* __restrict__ col, const int* __restrict__ batch,
                      const float* __restrict__ w1, const float* __restrict__ w2,
                      int* __restrict__ deg, int* __restrict__ pos_e, int* __restrict__ cnt,
                      float* __restrict__ wt1, float* __restrict__ wt2) {
    int e = blockIdx.x * 256 + threadIdx.x;
    if (e < N_EDGES) {
        int c = col[e];
        pos_e[e] = atomicAdd(&deg[c * DPAD], 1);
    }
    if (e < N_NODES) atomicAdd(&cnt[batch[e]], 1);
    if (e < EMB * IN_CH) {
        int j = e / IN_CH, k = e % IN_CH;
        wt1[k * EMB + j] = w1[e];
    } else if (e < EMB * IN_CH + EMB * EMB) {
        int t = e - EMB * IN_CH;
        int j = t / EMB, k = t % EMB;
        wt2[k * EMB + j] = w2[t];
    }
}

// ---------------- multi-block exclusive scan ----------------
__device__ inline int wave_incl_scan(int x, int lane) {
    #pragma unroll
    for (int off = 1; off < 64; off <<= 1) {
        int y = __shfl_up(x, off, 64);
        if (lane >= off) x += y;
    }
    return x;
}

__global__ void k_scan1(const int* __restrict__ in, int* __restrict__ part, int n) {
    __shared__ int ws[4];
    int i = blockIdx.x * 256 + threadIdx.x;
    int lane = threadIdx.x & 63, wid = threadIdx.x >> 6;
    int v = (i < n) ? in[i * DPAD] : 0;
    int x = wave_incl_scan(v, lane);
    if (lane == 63) ws[wid] = x;
    __syncthreads();
    if (threadIdx.x == 0) part[blockIdx.x] = ws[0] + ws[1] + ws[2] + ws[3];
}

// block 0: exclusive scan of part[nb]; block 1: digitize(dd)->rankx
__global__ void k_scan2d(int* __restrict__ part, int nb,
                         const int* __restrict__ dd, int* __restrict__ rankx) {
    int t = threadIdx.x, lane = t & 63, wid = t >> 6;
    if (blockIdx.x == 0) {
        __shared__ int ws[4];
        int v = (t < nb) ? part[t] : 0;
        int x = wave_incl_scan(v, lane);
        if (lane == 63) ws[wid] = x;
        __syncthreads();
        int add = 0;
        for (int w = 0; w < wid; ++w) add += ws[w];
        if (t < nb) part[t] = x - v + add;   // exclusive
    } else {
        __shared__ int pres[N_GRAPHS];
        __shared__ int ws2[4];
        __shared__ int carry;
        for (int i = t; i < N_GRAPHS; i += 256) pres[i] = 0;
        __syncthreads();
        for (int i = t; i < 2 * N_PAIRS; i += 256) pres[dd[i]] = 1;
        if (t == 0) carry = 0;
        __syncthreads();
        for (int base = 0; base < N_GRAPHS; base += 256) {
            int i = base + t;
            int v = (i < N_GRAPHS) ? pres[i] : 0;
            int x = wave_incl_scan(v, lane);
            if (lane == 63) ws2[wid] = x;
            __syncthreads();
            int add = carry;
            for (int w = 0; w < wid; ++w) add += ws2[w];
            if (i < N_GRAPHS) rankx[i] = x - v + add;
            __syncthreads();
            if (t == 255) carry = add + x;
            __syncthreads();
        }
    }
}

// scan3 + dinv + off sentinel fused (reads padded deg)
__global__ void k_scan3d(const int* __restrict__ in, const int* __restrict__ part,
                         int* __restrict__ off, float* __restrict__ dinv) {
    __shared__ int ws[4];
    int i = blockIdx.x * 256 + threadIdx.x;
    int lane = threadIdx.x & 63, wid = threadIdx.x >> 6;
    int v = (i < N_NODES) ? in[i * DPAD] : 0;
    int x = wave_incl_scan(v, lane);
    if (lane == 63) ws[wid] = x;
    __syncthreads();
    int add = part[blockIdx.x];
    for (int w = 0; w < wid; ++w) add += ws[w];
    if (i < N_NODES) {
        off[i] = x - v + add;
        dinv[i] = 1.0f / sqrtf((float)(v + 1));   // +1 self loop
    }
    if (i == 0) off[N_NODES] = N_EDGES;
}

// ---------------- CSR fill (atomic-free) + xs = x*dinv scale, one kernel ----------------
__global__ void k_fill_scale(const int* __restrict__ row, const int* __restrict__ col,
                             const int* __restrict__ pos_e, const int* __restrict__ off,
                             int* __restrict__ csr_row,
                             const float4* __restrict__ x, const float* __restrict__ dinv,
                             float4* __restrict__ xs) {
    int idx = blockIdx.x * 256 + threadIdx.x;
    if (idx < N_EDGES) {
        int c = col[idx];
        int p = pos_e[idx];
        csr_row[off[c] + p] = row[idx];
    } else {
        int i = idx - N_EDGES;           // exactly N_NODES*16 of these
        int n = i >> 4;
        float d = dinv[n];
        float4 v = x[i];
        v.x *= d; v.y *= d; v.z *= d; v.w *= d;
        xs[i] = v;
    }
}

__device__ inline void f4add(float4& a, const float4 b) {
    a.x += b.x; a.y += b.y; a.z += b.z; a.w += b.w;
}

// ---------------- conv1 fused: gather xs(64ch) -> LDS -> barrier -> GEMM1 from LDS broadcast ----------------
// 32 nodes/block, 256 threads. Phase A: 16 lanes/node x 2 node-groups. Phase B: 8x4 rowsxcols grid.
__global__ __launch_bounds__(256) void k_conv1f(
        const float4* __restrict__ xs, const int* __restrict__ csr_row,
        const int* __restrict__ off, const float* __restrict__ dinv,
        const float* __restrict__ w1t, const float* __restrict__ b1,
        float* __restrict__ h1s) {
    __shared__ __align__(16) float a_lds[32 * IN_CH];   // 8 KB
    int t = threadIdx.x;
    int base = blockIdx.x * 32;
    {   // phase A: gather + normalize into LDS
        int c4 = t & 15;
        #pragma unroll
        for (int g = 0; g < 2; ++g) {
            int nl = (t >> 4) + g * 16;
            int n = base + nl;
            float4 acc = make_float4(0.f, 0.f, 0.f, 0.f);
            if (n < N_NODES) {
                int s = off[n], e = off[n + 1];
                acc = xs[n * 16 + c4];       // self term
                int i = s;
                for (; i + 8 <= e; i += 8) {
                    int r0 = csr_row[i + 0], r1 = csr_row[i + 1], r2 = csr_row[i + 2], r3 = csr_row[i + 3];
                    int r4 = csr_row[i + 4], r5 = csr_row[i + 5], r6 = csr_row[i + 6], r7 = csr_row[i + 7];
                    float4 a0 = xs[r0 * 16 + c4], a1 = xs[r1 * 16 + c4];
                    float4 a2 = xs[r2 * 16 + c4], a3 = xs[r3 * 16 + c4];
                    float4 a4 = xs[r4 * 16 + c4], a5 = xs[r5 * 16 + c4];
                    float4 a6 = xs[r6 * 16 + c4], a7 = xs[r7 * 16 + c4];
                    f4add(a0, a1); f4add(a2, a3); f4add(a4, a5); f4add(a6, a7);
                    f4add(a0, a2); f4add(a4, a6);
                    f4add(a0, a4);
                    f4add(acc, a0);
                }
                for (; i < e; ++i) {
                    float4 a = xs[csr_row[i] * 16 + c4];
                    f4add(acc, a);
                }
                float dn = dinv[n];
                acc.x *= dn; acc.y *= dn; acc.z *= dn; acc.w *= dn;
            }
            *reinterpret_cast<float4*>(&a_lds[nl * IN_CH + c4 * 4]) = acc;
        }
    }
    __syncthreads();
    {   // phase B: h1s = relu(a.W1t + b1) * dinv   (rows rg*4..rg*4+3, cols cq..cq+3)
        int cq = (t & 31) << 2;
        int rg = t >> 5;              // 0..7
        float4 acc[4];
        #pragma unroll
        for (int r = 0; r < 4; ++r) acc[r] = make_float4(0.f, 0.f, 0.f, 0.f);
        #pragma unroll 2
        for (int k = 0; k < IN_CH; k += 4) {
            float4 w0 = *reinterpret_cast<const float4*>(&w1t[(k + 0) * EMB + cq]);
            float4 w1 = *reinterpret_cast<const float4*>(&w1t[(k + 1) * EMB + cq]);
            float4 w2 = *reinterpret_cast<const float4*>(&w1t[(k + 2) * EMB + cq]);
            float4 w3 = *reinterpret_cast<const float4*>(&w1t[(k + 3) * EMB + cq]);
            #pragma unroll
            for (int r = 0; r < 4; ++r) {
                float4 a = *reinterpret_cast<const float4*>(&a_lds[(rg * 4 + r) * IN_CH + k]);
                acc[r].x = fmaf(a.x, w0.x, fmaf(a.y, w1.x, fmaf(a.z, w2.x, fmaf(a.w, w3.x, acc[r].x))));
                acc[r].y = fmaf(a.x, w0.y, fmaf(a.y, w1.y, fmaf(a.z, w2.y, fmaf(a.w, w3.y, acc[r].y))));
                acc[r].z = fmaf(a.x, w0.z, fmaf(a.y, w1.z, fmaf(a.z, w2.z, fmaf(a.w, w3.z, acc[r].z))));
                acc[r].w = fmaf(a.x, w0.w, fmaf(a.y, w1.w, fmaf(a.z, w2.w, fmaf(a.w, w3.w, acc[r].w))));
            }
        }
        float4 bv = *reinterpret_cast<const float4*>(&b1[cq]);
        #pragma unroll
        for (int r = 0; r < 4; ++r) {
            int row = base + rg * 4 + r;
            if (row < N_NODES) {
                float4 v = acc[r];
                v.x += bv.x; v.y += bv.y; v.z += bv.z; v.w += bv.w;
                float sc = dinv[row];
                v.x = fmaxf(v.x, 0.f) * sc; v.y = fmaxf(v.y, 0.f) * sc;
                v.z = fmaxf(v.z, 0.f) * sc; v.w = fmaxf(v.w, 0.f) * sc;
                *reinterpret_cast<float4*>(&h1s[(size_t)row * EMB + cq]) = v;
            }
        }
    }
}

// ---------------- GEMM v5: A-tile staged in LDS (contiguous), barrier-free k-loop ----------------
template <int K>
__global__ void k_gemmv5(const float* __restrict__ A, const float* __restrict__ Wt,
                         float* __restrict__ out) {
    __shared__ __align__(16) float a_lds[64 * K];
    int t = threadIdx.x;
    {
        const float4* Ag = reinterpret_cast<const float4*>(A + (size_t)blockIdx.x * 64 * K);
        float4* Al = reinterpret_cast<float4*>(a_lds);
        constexpr int NV = (64 * K) / (4 * 256);
        #pragma unroll
        for (int i = 0; i < NV; ++i) Al[t + i * 256] = Ag[t + i * 256];
    }
    __syncthreads();
    int cq = (t & 31) << 2;
    int rg = t >> 5;
    float4 acc[8];
    #pragma unroll
    for (int r = 0; r < 8; ++r) acc[r] = make_float4(0.f, 0.f, 0.f, 0.f);
    #pragma unroll 2
    for (int k = 0; k < K; k += 4) {
        float4 w0 = *reinterpret_cast<const float4*>(&Wt[(k + 0) * EMB + cq]);
        float4 w1 = *reinterpret_cast<const float4*>(&Wt[(k + 1) * EMB + cq]);
        float4 w2 = *reinterpret_cast<const float4*>(&Wt[(k + 2) * EMB + cq]);
        float4 w3 = *reinterpret_cast<const float4*>(&Wt[(k + 3) * EMB + cq]);
        #pragma unroll
        for (int r = 0; r < 8; ++r) {
            float4 a = *reinterpret_cast<const float4*>(&a_lds[(rg * 8 + r) * K + k]);
            acc[r].x = fmaf(a.x, w0.x, fmaf(a.y, w1.x, fmaf(a.z, w2.x, fmaf(a.w, w3.x, acc[r].x))));
            acc[r].y = fmaf(a.x, w0.y, fmaf(a.y, w1.y, fmaf(a.z, w2.y, fmaf(a.w, w3.y, acc[r].y))));
            acc[r].z = fmaf(a.x, w0.z, fmaf(a.y, w1.z, fmaf(a.z, w2.z, fmaf(a.w, w3.z, acc[r].z))));
            acc[r].w = fmaf(a.x, w0.w, fmaf(a.y, w1.w, fmaf(a.z, w2.w, fmaf(a.w, w3.w, acc[r].w))));
        }
    }
    int row0 = blockIdx.x * 64 + rg * 8;
    #pragma unroll
    for (int r = 0; r < 8; ++r) {
        int row = row0 + r;
        if (row < N_NODES) {
            *reinterpret_cast<float4*>(&out[(size_t)row * EMB + cq]) = acc[r];
        }
    }
}

// ---------------- conv2 gather half-pass: 256B rows from t2, + bias/relu/dinv + run-based readout ----------------
template <int HALF>
__global__ void k_gro_h(const float4* __restrict__ t2, const int* __restrict__ csr_row,
                        const int* __restrict__ off, const float* __restrict__ dinv,
                        const float* __restrict__ bias, const int* __restrict__ batch,
                        float* __restrict__ gsum) {
    constexpr int NPB = 16;
    __shared__ __align__(16) float hb[NPB][64];
    __shared__ int bg[NPB];
    int t = threadIdx.x;
    int local = t >> 4;               // 0..15
    int c4 = t & 15;                  // float4 lane within the 64-ch half
    int n0 = blockIdx.x * NPB;
    int n = n0 + local;
    if (t < NPB) bg[t] = batch[n0 + t];
    int s = off[n], e = off[n + 1];
    const int cidx = HALF * 16 + c4;
    float4 acc = t2[(size_t)n * 32 + cidx];      // self term
    int i = s;
    for (; i + 8 <= e; i += 8) {
        int r0 = csr_row[i + 0], r1 = csr_row[i + 1], r2 = csr_row[i + 2], r3 = csr_row[i + 3];
        int r4 = csr_row[i + 4], r5 = csr_row[i + 5], r6 = csr_row[i + 6], r7 = csr_row[i + 7];
        float4 a0 = t2[(size_t)r0 * 32 + cidx], a1 = t2[(size_t)r1 * 32 + cidx];
        float4 a2 = t2[(size_t)r2 * 32 + cidx], a3 = t2[(size_t)r3 * 32 + cidx];
        float4 a4 = t2[(size_t)r4 * 32 + cidx], a5 = t2[(size_t)r5 * 32 + cidx];
        float4 a6 = t2[(size_t)r6 * 32 + cidx], a7 = t2[(size_t)r7 * 32 + cidx];
        f4add(a0, a1); f4add(a2, a3); f4add(a4, a5); f4add(a6, a7);
        f4add(a0, a2); f4add(a4, a6);
        f4add(a0, a4);
        f4add(acc, a0);
    }
    for (; i < e; ++i) {
        float4 a = t2[(size_t)csr_row[i] * 32 + cidx];
        f4add(acc, a);
    }
    float dn = dinv[n];
    float4 b = reinterpret_cast<const float4*>(bias)[cidx];
    acc.x = fmaxf(fmaf(acc.x, dn, b.x), 0.f);
    acc.y = fmaxf(fmaf(acc.y, dn, b.y), 0.f);
    acc.z = fmaxf(fmaf(acc.z, dn, b.z), 0.f);
    acc.w = fmaxf(fmaf(acc.w, dn, b.w), 0.f);
    *reinterpret_cast<float4*>(&hb[local][c4 * 4]) = acc;
    __syncthreads();
    {   // readout: ch = t&63 within half, quarter q scans 4 rows
        int ch = t & 63, q = t >> 6;
        int j0 = q * 4;
        int g = bg[j0];
        float a = 0.f;
        #pragma unroll
        for (int j = j0; j < j0 + 4; ++j) {
            int gj = bg[j];
            if (gj != g) { atomicAdd(&gsum[g * EMB + HALF * 64 + ch], a); a = 0.f; g = gj; }
            a += hb[j][ch];
        }
        atomicAdd(&gsum[g * EMB + HALF * 64 + ch], a);
    }
}

// ---------------- pair MLP, 16 pairs/block, mean-division fused at load ----------------
__global__ void k_mlp16(const float* __restrict__ gemb, const int* __restrict__ cnt,
                        const int* __restrict__ dd, const int* __restrict__ rankx,
                        const float* __restrict__ w1, const float* __restrict__ b1,
                        const float* __restrict__ w2, const float* __restrict__ b2,
                        float* __restrict__ out) {
    __shared__ __align__(16) float pv[PPB][2 * EMB];
    __shared__ float wpart[4][PPB];
    int p0 = blockIdx.x * PPB;
    int t = threadIdx.x;             // 0..255
    int lane = t & 63, wid = t >> 6;
    #pragma unroll
    for (int j = 0; j < PPB; ++j) {
        int p = p0 + j;
        if (t < EMB) {
            int ga = rankx[dd[p]];
            int ca = cnt[ga];
            float ra = 1.0f / (float)(ca > 1 ? ca : 1);
            pv[j][t] = gemb[ga * EMB + t] * ra;
        } else {
            int gb = rankx[dd[N_PAIRS + p]];
            int cb = cnt[gb];
            float rb = 1.0f / (float)(cb > 1 ? cb : 1);
            pv[j][t] = gemb[gb * EMB + (t - EMB)] * rb;
        }
    }
    __syncthreads();
    float acc[PPB];
    float bv = b1[t];
    #pragma unroll
    for (int j = 0; j < PPB; ++j) acc[j] = bv;
    const float4* wrow = reinterpret_cast<const float4*>(&w1[t * 2 * EMB]);
    for (int k = 0; k < (2 * EMB) / 4; ++k) {
        float4 w = wrow[k];
        #pragma unroll
        for (int j = 0; j < PPB; ++j) {
            const float4 xv = *reinterpret_cast<const float4*>(&pv[j][k * 4]);
            acc[j] = fmaf(xv.x, w.x, fmaf(xv.y, w.y, fmaf(xv.z, w.z, fmaf(xv.w, w.w, acc[j]))));
        }
    }
    float w2t = w2[t];
    float contrib[PPB];
    #pragma unroll
    for (int j = 0; j < PPB; ++j) contrib[j] = fmaxf(acc[j], 0.f) * w2t;
    #pragma unroll
    for (int off = 32; off > 0; off >>= 1) {
        #pragma unroll
        for (int j = 0; j < PPB; ++j) contrib[j] += __shfl_down(contrib[j], off, 64);
    }
    if (lane == 0) {
        #pragma unroll
        for (int j = 0; j < PPB; ++j) wpart[wid][j] = contrib[j];
    }
    __syncthreads();
    if (t < PPB) {
        out[p0 + t] = wpart[0][t] + wpart[1][t] + wpart[2][t] + wpart[3][t] + b2[0];
    }
}

extern "C" void kernel_launch(void* const* d_in, const int* in_sizes, int n_in,
                              void* d_out, int out_size, void* d_ws, size_t ws_size,
                              hipStream_t stream) {
    const float* x        = (const float*)d_in[0];
    const int*   ei       = (const int*)d_in[1];      // [2, E]
    const int*   batch    = (const int*)d_in[2];
    const int*   dd       = (const int*)d_in[3];      // [2, P]
    const float* conv1_w  = (const float*)d_in[4];
    const float* conv1_b  = (const float*)d_in[5];
    const float* conv2_w  = (const float*)d_in[6];
    const float* conv2_b  = (const float*)d_in[7];
    const float* reg1_w   = (const float*)d_in[8];
    const float* reg1_b   = (const float*)d_in[9];
    const float* reg2_w   = (const float*)d_in[10];
    const float* reg2_b   = (const float*)d_in[11];
    float* outp = (float*)d_out;

    const int* ei_row = ei;
    const int* ei_col = ei + N_EDGES;

    // ---- workspace layout ----
    char* ws = (char*)d_ws;
    size_t o = 0;
    auto alloc = [&](size_t bytes) -> void* {
        void* p = ws + o;
        o = (o + bytes + 255) & ~(size_t)255;
        return p;
    };
    size_t zero_start = o;
    int*   deg     = (int*)alloc((size_t)N_NODES * DPAD * 4);   // one 64B line per counter
    int*   cnt     = (int*)alloc(N_GRAPHS * 4);
    float* gsum    = (float*)alloc(N_GRAPHS * EMB * 4);
    size_t zero_bytes = o - zero_start;
    int*   off     = (int*)alloc((N_NODES + 1) * 4);
    float* dinv    = (float*)alloc(N_NODES * 4);
    int*   part    = (int*)alloc(256 * 4);
    int*   pos_e   = (int*)alloc(N_EDGES * 4);
    int*   csr_row = (int*)alloc(N_EDGES * 4);
    int*   rankx   = (int*)alloc(N_GRAPHS * 4);
    float* Wt1     = (float*)alloc(IN_CH * EMB * 4);
    float* Wt2     = (float*)alloc(EMB * EMB * 4);
    float* h1s     = (float*)alloc((size_t)N_PAD * EMB * 4);
    float* t2      = (float*)alloc((size_t)N_PAD * EMB * 4);
    float* xs      = t2;   // xs (12.8MB) dead before GEMM2 writes t2

    (void)ws_size; (void)in_sizes; (void)n_in; (void)out_size;

    // zero deg/cnt/gsum (~4.3 MB)
    {
        int n4 = (int)(zero_bytes / 16);
        k_zero<<<(n4 + 255) / 256, 256, 0, stream>>>((float4*)(ws + zero_start), n4);
    }

    // pre: deg + per-edge rank + graph counts + weight transposes
    k_pre<<<N_EDGES / 256, 256, 0, stream>>>(ei_col, batch, conv1_w, conv2_w,
                                             deg, pos_e, cnt, Wt1, Wt2);
    {
        int nb = (N_NODES + 255) / 256;   // 196
        k_scan1<<<nb, 256, 0, stream>>>(deg, part, N_NODES);
        k_scan2d<<<2, 256, 0, stream>>>(part, nb, dd, rankx);   // + digitize in block 1
        k_scan3d<<<nb, 256, 0, stream>>>(deg, part, off, dinv);
    }
    k_fill_scale<<<(N_EDGES + N_NODES * (IN_CH / 4)) / 256, 256, 0, stream>>>(
        ei_row, ei_col, pos_e, off, csr_row, (const float4*)x, dinv, (float4*)xs);

    // conv1 fused: gather(64ch)->LDS->GEMM1(+bias,relu,dinv postscale)
    k_conv1f<<<N_PAD / 32, 256, 0, stream>>>(
        (const float4*)xs, csr_row, off, dinv, Wt1, conv1_b, h1s);

    // conv2: GEMM (LDS-A), then channel-split gather halves with fused bias/relu/readout
    k_gemmv5<EMB><<<N_PAD / 64, 256, 0, stream>>>(h1s, Wt2, t2);
    k_gro_h<0><<<N_NODES / 16, 256, 0, stream>>>(
        (const float4*)t2, csr_row, off, dinv, conv2_b, batch, gsum);
    k_gro_h<1><<<N_NODES / 16, 256, 0, stream>>>(
        (const float4*)t2, csr_row, off, dinv, conv2_b, batch, gsum);

    // pair MLP (mean division fused)
    k_mlp16<<<N_PAIRS / PPB, 256, 0, stream>>>(gsum, cnt, dd, rankx,
                                               reg1_w, reg1_b, reg2_w, reg2_b, outp);
}

// Round 16
// 227.158 us; speedup vs baseline: 1.7788x; 1.0342x over previous
//
#include <hip/hip_runtime.h>

#define N_NODES  50000
#define N_PAD    50048
#define N_EDGES  800000
#define N_GRAPHS 2000
#define N_PAIRS  4096
#define IN_CH    64
#define EMB      128
#define HID      256
#define PPB      16
#define DPAD     16    // deg counter padding: one 64B line per counter

__device__ inline int wave_incl_scan(int x, int lane) {
    #pragma unroll
    for (int off = 1; off < 64; off <<= 1) {
        int y = __shfl_up(x, off, 64);
        if (lane >= off) x += y;
    }
    return x;
}

// ---------------- zero-fill + digitize (independent work, one launch) ----------------
// blocks 0..nzb-1: zero; block nzb: digitize(dd)->rankx
__global__ void k_zero_dig(float4* __restrict__ p, int n4,
                           const int* __restrict__ dd, int* __restrict__ rankx) {
    int nzb = (n4 + 255) >> 8;
    int t = threadIdx.x, lane = t & 63, wid = t >> 6;
    if ((int)blockIdx.x < nzb) {
        int i = blockIdx.x * 256 + t;
        if (i < n4) p[i] = make_float4(0.f, 0.f, 0.f, 0.f);
    } else {
        __shared__ int pres[N_GRAPHS];
        __shared__ int ws2[4];
        __shared__ int carry;
        for (int i = t; i < N_GRAPHS; i += 256) pres[i] = 0;
        __syncthreads();
        for (int i = t; i < 2 * N_PAIRS; i += 256) pres[dd[i]] = 1;
        if (t == 0) carry = 0;
        __syncthreads();
        for (int base = 0; base < N_GRAPHS; base += 256) {
            int i = base + t;
            int v = (i < N_GRAPHS) ? pres[i] : 0;
            int x = wave_incl_scan(v, lane);
            if (lane == 63) ws2[wid] = x;
            __syncthreads();
            int add = carry;
            for (int w = 0; w < wid; ++w) add += ws2[w];
            if (i < N_GRAPHS) rankx[i] = x - v + add;
            __syncthreads();
            if (t == 255) carry = add + x;
            __syncthreads();
        }
    }
}

// ---------------- pre pass: in-degree (line-padded atomics) + per-edge rank + graph counts + transposes ----------------
__global__ void k_pre(const int* __restrict__ col, const int* __restrict__ batch,
                      const float* __restrict__ w1, const float* __restrict__ w2,
                      int* __restrict__ deg, int* __restrict__ pos_e, int* __restrict__ cnt,
                      float* __restrict__ wt1, float* __restrict__ wt2) {
    int e = blockIdx.x * 256 + threadIdx.x;
    if (e < N_EDGES) {
        int c = col[e];
        pos_e[e] = atomicAdd(&deg[c * DPAD], 1);
    }
    if (e < N_NODES) atomicAdd(&cnt[batch[e]], 1);
    if (e < EMB * IN_CH) {
        int j = e / IN_CH, k = e % IN_CH;
        wt1[k * EMB + j] = w1[e];
    } else if (e < EMB * IN_CH + EMB * EMB) {
        int t = e - EMB * IN_CH;
        int j = t / EMB, k = t % EMB;
        wt2[k * EMB + j] = w2[t];
    }
}

// ---------------- scan1: per-block sums of padded deg ----------------
__global__ void k_scan1(const int* __restrict__ in, int* __restrict__ part, int n) {
    __shared__ int ws[4];
    int i = blockIdx.x * 256 + threadIdx.x;
    int lane = threadIdx.x & 63, wid = threadIdx.x >> 6;
    int v = (i < n) ? in[i * DPAD] : 0;
    int x = wave_incl_scan(v, lane);
    if (lane == 63) ws[wid] = x;
    __syncthreads();
    if (threadIdx.x == 0) part[blockIdx.x] = ws[0] + ws[1] + ws[2] + ws[3];
}

// ---------------- scan3: self-computed part prefix + local scan + dinv + sentinel ----------------
__global__ void k_scan3d(const int* __restrict__ in, const int* __restrict__ part,
                         int* __restrict__ off, float* __restrict__ dinv) {
    __shared__ int ws[4];
    __shared__ int psum[4];
    int t = threadIdx.x;
    int lane = t & 63, wid = t >> 6;
    // block-parallel prefix of part[0..bid-1]
    int pp = 0;
    for (int w = t; w < (int)blockIdx.x; w += 256) pp += part[w];
    #pragma unroll
    for (int o = 32; o > 0; o >>= 1) pp += __shfl_down(pp, o, 64);
    if (lane == 0) psum[wid] = pp;
    // local scan
    int i = blockIdx.x * 256 + t;
    int v = (i < N_NODES) ? in[i * DPAD] : 0;
    int x = wave_incl_scan(v, lane);
    if (lane == 63) ws[wid] = x;
    __syncthreads();
    int add = psum[0] + psum[1] + psum[2] + psum[3];
    for (int w = 0; w < wid; ++w) add += ws[w];
    if (i < N_NODES) {
        off[i] = x - v + add;
        dinv[i] = 1.0f / sqrtf((float)(v + 1));   // +1 self loop
    }
    if (i == 0) off[N_NODES] = N_EDGES;
}

// ---------------- CSR fill (atomic-free) + xs = x*dinv scale, one kernel ----------------
__global__ void k_fill_scale(const int* __restrict__ row, const int* __restrict__ col,
                             const int* __restrict__ pos_e, const int* __restrict__ off,
                             int* __restrict__ csr_row,
                             const float4* __restrict__ x, const float* __restrict__ dinv,
                             float4* __restrict__ xs) {
    int idx = blockIdx.x * 256 + threadIdx.x;
    if (idx < N_EDGES) {
        int c = col[idx];
        int p = pos_e[idx];
        csr_row[off[c] + p] = row[idx];
    } else {
        int i = idx - N_EDGES;           // exactly N_NODES*16 of these
        int n = i >> 4;
        float d = dinv[n];
        float4 v = x[i];
        v.x *= d; v.y *= d; v.z *= d; v.w *= d;
        xs[i] = v;
    }
}

__device__ inline void f4add(float4& a, const float4 b) {
    a.x += b.x; a.y += b.y; a.z += b.z; a.w += b.w;
}

// ---------------- conv1 fused: gather xs(64ch, two 128B half-row epochs) -> LDS -> GEMM1 ----------------
// 32 nodes/block, 256 threads. Phase A: 8 lanes/node, 2 channel epochs. Phase B: 8x4 rowsxcols grid.
__global__ __launch_bounds__(256) void k_conv1f(
        const float4* __restrict__ xs, const int* __restrict__ csr_row,
        const int* __restrict__ off, const float* __restrict__ dinv,
        const float* __restrict__ w1t, const float* __restrict__ b1,
        float* __restrict__ h1s) {
    __shared__ __align__(16) float a_lds[32 * IN_CH];   // 8 KB
    int t = threadIdx.x;
    int base = blockIdx.x * 32;
    {   // phase A: gather + normalize into LDS, channel-epoch split (hot set 6.4 MB/epoch)
        int c4l = t & 7;
        int nl = t >> 3;              // 0..31
        int n = base + nl;
        int s = 0, e = 0;
        float dn = 0.f;
        if (n < N_NODES) { s = off[n]; e = off[n + 1]; dn = dinv[n]; }
        #pragma unroll
        for (int g = 0; g < 2; ++g) {
            int c4 = c4l + g * 8;
            float4 acc = make_float4(0.f, 0.f, 0.f, 0.f);
            if (n < N_NODES) {
                acc = xs[n * 16 + c4];       // self term
                int i = s;
                for (; i + 8 <= e; i += 8) {
                    int r0 = csr_row[i + 0], r1 = csr_row[i + 1], r2 = csr_row[i + 2], r3 = csr_row[i + 3];
                    int r4 = csr_row[i + 4], r5 = csr_row[i + 5], r6 = csr_row[i + 6], r7 = csr_row[i + 7];
                    float4 a0 = xs[r0 * 16 + c4], a1 = xs[r1 * 16 + c4];
                    float4 a2 = xs[r2 * 16 + c4], a3 = xs[r3 * 16 + c4];
                    float4 a4 = xs[r4 * 16 + c4], a5 = xs[r5 * 16 + c4];
                    float4 a6 = xs[r6 * 16 + c4], a7 = xs[r7 * 16 + c4];
                    f4add(a0, a1); f4add(a2, a3); f4add(a4, a5); f4add(a6, a7);
                    f4add(a0, a2); f4add(a4, a6);
                    f4add(a0, a4);
                    f4add(acc, a0);
                }
                for (; i < e; ++i) {
                    float4 a = xs[csr_row[i] * 16 + c4];
                    f4add(acc, a);
                }
                acc.x *= dn; acc.y *= dn; acc.z *= dn; acc.w *= dn;
            }
            *reinterpret_cast<float4*>(&a_lds[nl * IN_CH + c4 * 4]) = acc;
        }
    }
    __syncthreads();
    {   // phase B: h1s = relu(a.W1t + b1) * dinv   (rows rg*4..rg*4+3, cols cq..cq+3)
        int cq = (t & 31) << 2;
        int rg = t >> 5;              // 0..7
        float4 acc[4];
        #pragma unroll
        for (int r = 0; r < 4; ++r) acc[r] = make_float4(0.f, 0.f, 0.f, 0.f);
        #pragma unroll 2
        for (int k = 0; k < IN_CH; k += 4) {
            float4 w0 = *reinterpret_cast<const float4*>(&w1t[(k + 0) * EMB + cq]);
            float4 w1 = *reinterpret_cast<const float4*>(&w1t[(k + 1) * EMB + cq]);
            float4 w2 = *reinterpret_cast<const float4*>(&w1t[(k + 2) * EMB + cq]);
            float4 w3 = *reinterpret_cast<const float4*>(&w1t[(k + 3) * EMB + cq]);
            #pragma unroll
            for (int r = 0; r < 4; ++r) {
                float4 a = *reinterpret_cast<const float4*>(&a_lds[(rg * 4 + r) * IN_CH + k]);
                acc[r].x = fmaf(a.x, w0.x, fmaf(a.y, w1.x, fmaf(a.z, w2.x, fmaf(a.w, w3.x, acc[r].x))));
                acc[r].y = fmaf(a.x, w0.y, fmaf(a.y, w1.y, fmaf(a.z, w2.y, fmaf(a.w, w3.y, acc[r].y))));
                acc[r].z = fmaf(a.x, w0.z, fmaf(a.y, w1.z, fmaf(a.z, w2.z, fmaf(a.w, w3.z, acc[r].z))));
                acc[r].w = fmaf(a.x, w0.w, fmaf(a.y, w1.w, fmaf(a.z, w2.w, fmaf(a.w, w3.w, acc[r].w))));
            }
        }
        float4 bv = *reinterpret_cast<const float4*>(&b1[cq]);
        #pragma unroll
        for (int r = 0; r < 4; ++r) {
            int row = base + rg * 4 + r;
            if (row < N_NODES) {
                float4 v = acc[r];
                v.x += bv.x; v.y += bv.y; v.z += bv.z; v.w += bv.w;
                float sc = dinv[row];
                v.x = fmaxf(v.x, 0.f) * sc; v.y = fmaxf(v.y, 0.f) * sc;
                v.z = fmaxf(v.z, 0.f) * sc; v.w = fmaxf(v.w, 0.f) * sc;
                *reinterpret_cast<float4*>(&h1s[(size_t)row * EMB + cq]) = v;
            }
        }
    }
}

// ---------------- GEMM v5: A-tile staged in LDS (contiguous), barrier-free k-loop ----------------
template <int K>
__global__ void k_gemmv5(const float* __restrict__ A, const float* __restrict__ Wt,
                         float* __restrict__ out) {
    __shared__ __align__(16) float a_lds[64 * K];
    int t = threadIdx.x;
    {
        const float4* Ag = reinterpret_cast<const float4*>(A + (size_t)blockIdx.x * 64 * K);
        float4* Al = reinterpret_cast<float4*>(a_lds);
        constexpr int NV = (64 * K) / (4 * 256);
        #pragma unroll
        for (int i = 0; i < NV; ++i) Al[t + i * 256] = Ag[t + i * 256];
    }
    __syncthreads();
    int cq = (t & 31) << 2;
    int rg = t >> 5;
    float4 acc[8];
    #pragma unroll
    for (int r = 0; r < 8; ++r) acc[r] = make_float4(0.f, 0.f, 0.f, 0.f);
    #pragma unroll 2
    for (int k = 0; k < K; k += 4) {
        float4 w0 = *reinterpret_cast<const float4*>(&Wt[(k + 0) * EMB + cq]);
        float4 w1 = *reinterpret_cast<const float4*>(&Wt[(k + 1) * EMB + cq]);
        float4 w2 = *reinterpret_cast<const float4*>(&Wt[(k + 2) * EMB + cq]);
        float4 w3 = *reinterpret_cast<const float4*>(&Wt[(k + 3) * EMB + cq]);
        #pragma unroll
        for (int r = 0; r < 8; ++r) {
            float4 a = *reinterpret_cast<const float4*>(&a_lds[(rg * 8 + r) * K + k]);
            acc[r].x = fmaf(a.x, w0.x, fmaf(a.y, w1.x, fmaf(a.z, w2.x, fmaf(a.w, w3.x, acc[r].x))));
            acc[r].y = fmaf(a.x, w0.y, fmaf(a.y, w1.y, fmaf(a.z, w2.y, fmaf(a.w, w3.y, acc[r].y))));
            acc[r].z = fmaf(a.x, w0.z, fmaf(a.y, w1.z, fmaf(a.z, w2.z, fmaf(a.w, w3.z, acc[r].z))));
            acc[r].w = fmaf(a.x, w0.w, fmaf(a.y, w1.w, fmaf(a.z, w2.w, fmaf(a.w, w3.w, acc[r].w))));
        }
    }
    int row0 = blockIdx.x * 64 + rg * 8;
    #pragma unroll
    for (int r = 0; r < 8; ++r) {
        int row = row0 + r;
        if (row < N_NODES) {
            *reinterpret_cast<float4*>(&out[(size_t)row * EMB + cq]) = acc[r];
        }
    }
}

// ---------------- conv2 gather half-pass: 256B rows from t2, + bias/relu/dinv + run-based readout ----------------
template <int HALF>
__global__ void k_gro_h(const float4* __restrict__ t2, const int* __restrict__ csr_row,
                        const int* __restrict__ off, const float* __restrict__ dinv,
                        const float* __restrict__ bias, const int* __restrict__ batch,
                        float* __restrict__ gsum) {
    constexpr int NPB = 16;
    __shared__ __align__(16) float hb[NPB][64];
    __shared__ int bg[NPB];
    int t = threadIdx.x;
    int local = t >> 4;               // 0..15
    int c4 = t & 15;                  // float4 lane within the 64-ch half
    int n0 = blockIdx.x * NPB;
    int n = n0 + local;
    if (t < NPB) bg[t] = batch[n0 + t];
    int s = off[n], e = off[n + 1];
    const int cidx = HALF * 16 + c4;
    float4 acc = t2[(size_t)n * 32 + cidx];      // self term
    int i = s;
    for (; i + 8 <= e; i += 8) {
        int r0 = csr_row[i + 0], r1 = csr_row[i + 1], r2 = csr_row[i + 2], r3 = csr_row[i + 3];
        int r4 = csr_row[i + 4], r5 = csr_row[i + 5], r6 = csr_row[i + 6], r7 = csr_row[i + 7];
        float4 a0 = t2[(size_t)r0 * 32 + cidx], a1 = t2[(size_t)r1 * 32 + cidx];
        float4 a2 = t2[(size_t)r2 * 32 + cidx], a3 = t2[(size_t)r3 * 32 + cidx];
        float4 a4 = t2[(size_t)r4 * 32 + cidx], a5 = t2[(size_t)r5 * 32 + cidx];
        float4 a6 = t2[(size_t)r6 * 32 + cidx], a7 = t2[(size_t)r7 * 32 + cidx];
        f4add(a0, a1); f4add(a2, a3); f4add(a4, a5); f4add(a6, a7);
        f4add(a0, a2); f4add(a4, a6);
        f4add(a0, a4);
        f4add(acc, a0);
    }
    for (; i < e; ++i) {
        float4 a = t2[(size_t)csr_row[i] * 32 + cidx];
        f4add(acc, a);
    }
    float dn = dinv[n];
    float4 b = reinterpret_cast<const float4*>(bias)[cidx];
    acc.x = fmaxf(fmaf(acc.x, dn, b.x), 0.f);
    acc.y = fmaxf(fmaf(acc.y, dn, b.y), 0.f);
    acc.z = fmaxf(fmaf(acc.z, dn, b.z), 0.f);
    acc.w = fmaxf(fmaf(acc.w, dn, b.w), 0.f);
    *reinterpret_cast<float4*>(&hb[local][c4 * 4]) = acc;
    __syncthreads();
    {   // readout: ch = t&63 within half, quarter q scans 4 rows
        int ch = t & 63, q = t >> 6;
        int j0 = q * 4;
        int g = bg[j0];
        float a = 0.f;
        #pragma unroll
        for (int j = j0; j < j0 + 4; ++j) {
            int gj = bg[j];
            if (gj != g) { atomicAdd(&gsum[g * EMB + HALF * 64 + ch], a); a = 0.f; g = gj; }
            a += hb[j][ch];
        }
        atomicAdd(&gsum[g * EMB + HALF * 64 + ch], a);
    }
}

// ---------------- pair MLP, 16 pairs/block, mean-division fused at load ----------------
__global__ void k_mlp16(const float* __restrict__ gemb, const int* __restrict__ cnt,
                        const int* __restrict__ dd, const int* __restrict__ rankx,
                        const float* __restrict__ w1, const float* __restrict__ b1,
                        const float* __restrict__ w2, const float* __restrict__ b2,
                        float* __restrict__ out) {
    __shared__ __align__(16) float pv[PPB][2 * EMB];
    __shared__ float wpart[4][PPB];
    int p0 = blockIdx.x * PPB;
    int t = threadIdx.x;             // 0..255
    int lane = t & 63, wid = t >> 6;
    #pragma unroll
    for (int j = 0; j < PPB; ++j) {
        int p = p0 + j;
        if (t < EMB) {
            int ga = rankx[dd[p]];
            int ca = cnt[ga];
            float ra = 1.0f / (float)(ca > 1 ? ca : 1);
            pv[j][t] = gemb[ga * EMB + t] * ra;
        } else {
            int gb = rankx[dd[N_PAIRS + p]];
            int cb = cnt[gb];
            float rb = 1.0f / (float)(cb > 1 ? cb : 1);
            pv[j][t] = gemb[gb * EMB + (t - EMB)] * rb;
        }
    }
    __syncthreads();
    float acc[PPB];
    float bv = b1[t];
    #pragma unroll
    for (int j = 0; j < PPB; ++j) acc[j] = bv;
    const float4* wrow = reinterpret_cast<const float4*>(&w1[t * 2 * EMB]);
    for (int k = 0; k < (2 * EMB) / 4; ++k) {
        float4 w = wrow[k];
        #pragma unroll
        for (int j = 0; j < PPB; ++j) {
            const float4 xv = *reinterpret_cast<const float4*>(&pv[j][k * 4]);
            acc[j] = fmaf(xv.x, w.x, fmaf(xv.y, w.y, fmaf(xv.z, w.z, fmaf(xv.w, w.w, acc[j]))));
        }
    }
    float w2t = w2[t];
    float contrib[PPB];
    #pragma unroll
    for (int j = 0; j < PPB; ++j) contrib[j] = fmaxf(acc[j], 0.f) * w2t;
    #pragma unroll
    for (int off = 32; off > 0; off >>= 1) {
        #pragma unroll
        for (int j = 0; j < PPB; ++j) contrib[j] += __shfl_down(contrib[j], off, 64);
    }
    if (lane == 0) {
        #pragma unroll
        for (int j = 0; j < PPB; ++j) wpart[wid][j] = contrib[j];
    }
    __syncthreads();
    if (t < PPB) {
        out[p0 + t] = wpart[0][t] + wpart[1][t] + wpart[2][t] + wpart[3][t] + b2[0];
    }
}

extern "C" void kernel_launch(void* const* d_in, const int* in_sizes, int n_in,
                              void* d_out, int out_size, void* d_ws, size_t ws_size,
                              hipStream_t stream) {
    const float* x        = (const float*)d_in[0];
    const int*   ei       = (const int*)d_in[1];      // [2, E]
    const int*   batch    = (const int*)d_in[2];
    const int*   dd       = (const int*)d_in[3];      // [2, P]
    const float* conv1_w  = (const float*)d_in[4];
    const float* conv1_b  = (const float*)d_in[5];
    const float* conv2_w  = (const float*)d_in[6];
    const float* conv2_b  = (const float*)d_in[7];
    const float* reg1_w   = (const float*)d_in[8];
    const float* reg1_b   = (const float*)d_in[9];
    const float* reg2_w   = (const float*)d_in[10];
    const float* reg2_b   = (const float*)d_in[11];
    float* outp = (float*)d_out;

    const int* ei_row = ei;
    const int* ei_col = ei + N_EDGES;

    // ---- workspace layout ----
    char* ws = (char*)d_ws;
    size_t o = 0;
    auto alloc = [&](size_t bytes) -> void* {
        void* p = ws + o;
        o = (o + bytes + 255) & ~(size_t)255;
        return p;
    };
    size_t zero_start = o;
    int*   deg     = (int*)alloc((size_t)N_NODES * DPAD * 4);   // one 64B line per counter
    int*   cnt     = (int*)alloc(N_GRAPHS * 4);
    float* gsum    = (float*)alloc(N_GRAPHS * EMB * 4);
    size_t zero_bytes = o - zero_start;
    int*   off     = (int*)alloc((N_NODES + 1) * 4);
    float* dinv    = (float*)alloc(N_NODES * 4);
    int*   part    = (int*)alloc(256 * 4);
    int*   pos_e   = (int*)alloc(N_EDGES * 4);
    int*   csr_row = (int*)alloc(N_EDGES * 4);
    int*   rankx   = (int*)alloc(N_GRAPHS * 4);
    float* Wt1     = (float*)alloc(IN_CH * EMB * 4);
    float* Wt2     = (float*)alloc(EMB * EMB * 4);
    float* h1s     = (float*)alloc((size_t)N_PAD * EMB * 4);
    float* t2      = (float*)alloc((size_t)N_PAD * EMB * 4);
    float* xs      = t2;   // xs (12.8MB) dead before GEMM2 writes t2

    (void)ws_size; (void)in_sizes; (void)n_in; (void)out_size;

    // zero deg/cnt/gsum (~4.3 MB) + digitize (extra block)
    {
        int n4 = (int)(zero_bytes / 16);
        int nzb = (n4 + 255) / 256;
        k_zero_dig<<<nzb + 1, 256, 0, stream>>>((float4*)(ws + zero_start), n4, dd, rankx);
    }

    // pre: deg + per-edge rank + graph counts + weight transposes
    k_pre<<<N_EDGES / 256, 256, 0, stream>>>(ei_col, batch, conv1_w, conv2_w,
                                             deg, pos_e, cnt, Wt1, Wt2);
    {
        int nb = (N_NODES + 255) / 256;   // 196
        k_scan1<<<nb, 256, 0, stream>>>(deg, part, N_NODES);
        k_scan3d<<<nb, 256, 0, stream>>>(deg, part, off, dinv);
    }
    k_fill_scale<<<(N_EDGES + N_NODES * (IN_CH / 4)) / 256, 256, 0, stream>>>(
        ei_row, ei_col, pos_e, off, csr_row, (const float4*)x, dinv, (float4*)xs);

    // conv1 fused: gather(64ch, 2 channel epochs)->LDS->GEMM1(+bias,relu,dinv postscale)
    k_conv1f<<<N_PAD / 32, 256, 0, stream>>>(
        (const float4*)xs, csr_row, off, dinv, Wt1, conv1_b, h1s);

    // conv2: GEMM (LDS-A), then channel-split gather halves with fused bias/relu/readout
    k_gemmv5<EMB><<<N_PAD / 64, 256, 0, stream>>>(h1s, Wt2, t2);
    k_gro_h<0><<<N_NODES / 16, 256, 0, stream>>>(
        (const float4*)t2, csr_row, off, dinv, conv2_b, batch, gsum);
    k_gro_h<1><<<N_NODES / 16, 256, 0, stream>>>(
        (const float4*)t2, csr_row, off, dinv, conv2_b, batch, gsum);

    // pair MLP (mean division fused)
    k_mlp16<<<N_PAIRS / PPB, 256, 0, stream>>>(gsum, cnt, dd, rankx,
                                               reg1_w, reg1_b, reg2_w, reg2_b, outp);
}

// Round 17
// 215.402 us; speedup vs baseline: 1.8759x; 1.0546x over previous
//
#include <hip/hip_runtime.h>

#define N_NODES  50000
#define N_PAD    50048
#define N_EDGES  800000
#define N_GRAPHS 2000
#define N_PAIRS  4096
#define IN_CH    64
#define EMB      128
#define HID      256
#define PPB      16
#define DPAD     16    // deg counter padding: one 64B line per counter
#define GROB     1563  // ceil(N_NODES/32)

__device__ inline int wave_incl_scan(int x, int lane) {
    #pragma unroll
    for (int off = 1; off < 64; off <<= 1) {
        int y = __shfl_up(x, off, 64);
        if (lane >= off) x += y;
    }
    return x;
}

// ---------------- zero-fill (deg + cnt only) ----------------
__global__ void k_zero(float4* __restrict__ p, int n4) {
    int i = blockIdx.x * 256 + threadIdx.x;
    if (i < n4) p[i] = make_float4(0.f, 0.f, 0.f, 0.f);
}

// ---------------- pre pass: deg atomics + pos_e + cnt + transposes + digitize + gsum zero ----------------
// blocks 0..3124: per-edge work; block 3125: digitize; blocks 3126..3141: gsum zero
__global__ void k_pre(const int* __restrict__ col, const int* __restrict__ batch,
                      const float* __restrict__ w1, const float* __restrict__ w2,
                      int* __restrict__ deg, int* __restrict__ pos_e, int* __restrict__ cnt,
                      float* __restrict__ wt1, float* __restrict__ wt2,
                      const int* __restrict__ dd, int* __restrict__ rankx,
                      float4* __restrict__ gsum4) {
    int b = blockIdx.x, t = threadIdx.x;
    if (b < N_EDGES / 256) {
        int e = b * 256 + t;
        int c = col[e];
        pos_e[e] = atomicAdd(&deg[c * DPAD], 1);
        if (e < N_NODES) atomicAdd(&cnt[batch[e]], 1);
        if (e < EMB * IN_CH) {
            int j = e / IN_CH, k = e % IN_CH;
            wt1[k * EMB + j] = w1[e];
        } else if (e < EMB * IN_CH + EMB * EMB) {
            int q = e - EMB * IN_CH;
            int j = q / EMB, k = q % EMB;
            wt2[k * EMB + j] = w2[q];
        }
    } else if (b == N_EDGES / 256) {
        __shared__ int pres[N_GRAPHS];
        __shared__ int ws2[4];
        __shared__ int carry;
        int lane = t & 63, wid = t >> 6;
        for (int i = t; i < N_GRAPHS; i += 256) pres[i] = 0;
        __syncthreads();
        for (int i = t; i < 2 * N_PAIRS; i += 256) pres[dd[i]] = 1;
        if (t == 0) carry = 0;
        __syncthreads();
        for (int base = 0; base < N_GRAPHS; base += 256) {
            int i = base + t;
            int v = (i < N_GRAPHS) ? pres[i] : 0;
            int x = wave_incl_scan(v, lane);
            if (lane == 63) ws2[wid] = x;
            __syncthreads();
            int add = carry;
            for (int w = 0; w < wid; ++w) add += ws2[w];
            if (i < N_GRAPHS) rankx[i] = x - v + add;
            __syncthreads();
            if (t == 255) carry = add + x;
            __syncthreads();
        }
    } else {
        // gsum zero: 2000*128 floats = 64000 float4
        int i = (b - N_EDGES / 256 - 1) * 256 + t;     // 0..4095
        for (int k = i; k < N_GRAPHS * EMB / 4; k += 4096)
            gsum4[k] = make_float4(0.f, 0.f, 0.f, 0.f);
    }
}

// ---------------- scan1: per-block sums of padded deg ----------------
__global__ void k_scan1(const int* __restrict__ in, int* __restrict__ part, int n) {
    __shared__ int ws[4];
    int i = blockIdx.x * 256 + threadIdx.x;
    int lane = threadIdx.x & 63, wid = threadIdx.x >> 6;
    int v = (i < n) ? in[i * DPAD] : 0;
    int x = wave_incl_scan(v, lane);
    if (lane == 63) ws[wid] = x;
    __syncthreads();
    if (threadIdx.x == 0) part[blockIdx.x] = ws[0] + ws[1] + ws[2] + ws[3];
}

// ---------------- scan3: self-computed part prefix + local scan + dinv + sentinel ----------------
__global__ void k_scan3d(const int* __restrict__ in, const int* __restrict__ part,
                         int* __restrict__ off, float* __restrict__ dinv) {
    __shared__ int ws[4];
    __shared__ int psum[4];
    int t = threadIdx.x;
    int lane = t & 63, wid = t >> 6;
    int pp = 0;
    for (int w = t; w < (int)blockIdx.x; w += 256) pp += part[w];
    #pragma unroll
    for (int o = 32; o > 0; o >>= 1) pp += __shfl_down(pp, o, 64);
    if (lane == 0) psum[wid] = pp;
    int i = blockIdx.x * 256 + t;
    int v = (i < N_NODES) ? in[i * DPAD] : 0;
    int x = wave_incl_scan(v, lane);
    if (lane == 63) ws[wid] = x;
    __syncthreads();
    int add = psum[0] + psum[1] + psum[2] + psum[3];
    for (int w = 0; w < wid; ++w) add += ws[w];
    if (i < N_NODES) {
        off[i] = x - v + add;
        dinv[i] = 1.0f / sqrtf((float)(v + 1));   // +1 self loop
    }
    if (i == 0) off[N_NODES] = N_EDGES;
}

// ---------------- CSR fill (atomic-free) + xs = x*dinv scale, one kernel ----------------
__global__ void k_fill_scale(const int* __restrict__ row, const int* __restrict__ col,
                             const int* __restrict__ pos_e, const int* __restrict__ off,
                             int* __restrict__ csr_row,
                             const float4* __restrict__ x, const float* __restrict__ dinv,
                             float4* __restrict__ xs) {
    int idx = blockIdx.x * 256 + threadIdx.x;
    if (idx < N_EDGES) {
        int c = col[idx];
        int p = pos_e[idx];
        csr_row[off[c] + p] = row[idx];
    } else {
        int i = idx - N_EDGES;           // exactly N_NODES*16 of these
        int n = i >> 4;
        float d = dinv[n];
        float4 v = x[i];
        v.x *= d; v.y *= d; v.z *= d; v.w *= d;
        xs[i] = v;
    }
}

__device__ inline void f4add(float4& a, const float4 b) {
    a.x += b.x; a.y += b.y; a.z += b.z; a.w += b.w;
}

// ---------------- conv1 fused: gather xs(64ch, two 128B epochs) -> LDS -> GEMM1 ----------------
__global__ __launch_bounds__(256) void k_conv1f(
        const float4* __restrict__ xs, const int* __restrict__ csr_row,
        const int* __restrict__ off, const float* __restrict__ dinv,
        const float* __restrict__ w1t, const float* __restrict__ b1,
        float* __restrict__ h1s) {
    __shared__ __align__(16) float a_lds[32 * IN_CH];   // 8 KB
    int t = threadIdx.x;
    int base = blockIdx.x * 32;
    {   // phase A: gather + normalize into LDS, channel-epoch split
        int c4l = t & 7;
        int nl = t >> 3;              // 0..31
        int n = base + nl;
        int s = 0, e = 0;
        float dn = 0.f;
        if (n < N_NODES) { s = off[n]; e = off[n + 1]; dn = dinv[n]; }
        #pragma unroll
        for (int g = 0; g < 2; ++g) {
            int c4 = c4l + g * 8;
            float4 acc = make_float4(0.f, 0.f, 0.f, 0.f);
            if (n < N_NODES) {
                acc = xs[n * 16 + c4];       // self term
                int i = s;
                for (; i + 8 <= e; i += 8) {
                    int r0 = csr_row[i + 0], r1 = csr_row[i + 1], r2 = csr_row[i + 2], r3 = csr_row[i + 3];
                    int r4 = csr_row[i + 4], r5 = csr_row[i + 5], r6 = csr_row[i + 6], r7 = csr_row[i + 7];
                    float4 a0 = xs[r0 * 16 + c4], a1 = xs[r1 * 16 + c4];
                    float4 a2 = xs[r2 * 16 + c4], a3 = xs[r3 * 16 + c4];
                    float4 a4 = xs[r4 * 16 + c4], a5 = xs[r5 * 16 + c4];
                    float4 a6 = xs[r6 * 16 + c4], a7 = xs[r7 * 16 + c4];
                    f4add(a0, a1); f4add(a2, a3); f4add(a4, a5); f4add(a6, a7);
                    f4add(a0, a2); f4add(a4, a6);
                    f4add(a0, a4);
                    f4add(acc, a0);
                }
                for (; i < e; ++i) {
                    float4 a = xs[csr_row[i] * 16 + c4];
                    f4add(acc, a);
                }
                acc.x *= dn; acc.y *= dn; acc.z *= dn; acc.w *= dn;
            }
            *reinterpret_cast<float4*>(&a_lds[nl * IN_CH + c4 * 4]) = acc;
        }
    }
    __syncthreads();
    {   // phase B: h1s = relu(a.W1t + b1) * dinv
        int cq = (t & 31) << 2;
        int rg = t >> 5;              // 0..7
        float4 acc[4];
        #pragma unroll
        for (int r = 0; r < 4; ++r) acc[r] = make_float4(0.f, 0.f, 0.f, 0.f);
        #pragma unroll 2
        for (int k = 0; k < IN_CH; k += 4) {
            float4 w0 = *reinterpret_cast<const float4*>(&w1t[(k + 0) * EMB + cq]);
            float4 w1 = *reinterpret_cast<const float4*>(&w1t[(k + 1) * EMB + cq]);
            float4 w2 = *reinterpret_cast<const float4*>(&w1t[(k + 2) * EMB + cq]);
            float4 w3 = *reinterpret_cast<const float4*>(&w1t[(k + 3) * EMB + cq]);
            #pragma unroll
            for (int r = 0; r < 4; ++r) {
                float4 a = *reinterpret_cast<const float4*>(&a_lds[(rg * 4 + r) * IN_CH + k]);
                acc[r].x = fmaf(a.x, w0.x, fmaf(a.y, w1.x, fmaf(a.z, w2.x, fmaf(a.w, w3.x, acc[r].x))));
                acc[r].y = fmaf(a.x, w0.y, fmaf(a.y, w1.y, fmaf(a.z, w2.y, fmaf(a.w, w3.y, acc[r].y))));
                acc[r].z = fmaf(a.x, w0.z, fmaf(a.y, w1.z, fmaf(a.z, w2.z, fmaf(a.w, w3.z, acc[r].z))));
                acc[r].w = fmaf(a.x, w0.w, fmaf(a.y, w1.w, fmaf(a.z, w2.w, fmaf(a.w, w3.w, acc[r].w))));
            }
        }
        float4 bv = *reinterpret_cast<const float4*>(&b1[cq]);
        #pragma unroll
        for (int r = 0; r < 4; ++r) {
            int row = base + rg * 4 + r;
            if (row < N_NODES) {
                float4 v = acc[r];
                v.x += bv.x; v.y += bv.y; v.z += bv.z; v.w += bv.w;
                float sc = dinv[row];
                v.x = fmaxf(v.x, 0.f) * sc; v.y = fmaxf(v.y, 0.f) * sc;
                v.z = fmaxf(v.z, 0.f) * sc; v.w = fmaxf(v.w, 0.f) * sc;
                *reinterpret_cast<float4*>(&h1s[(size_t)row * EMB + cq]) = v;
            }
        }
    }
}

// ---------------- GEMM v5: A-tile staged in LDS (contiguous), barrier-free k-loop ----------------
template <int K>
__global__ void k_gemmv5(const float* __restrict__ A, const float* __restrict__ Wt,
                         float* __restrict__ out) {
    __shared__ __align__(16) float a_lds[64 * K];
    int t = threadIdx.x;
    {
        const float4* Ag = reinterpret_cast<const float4*>(A + (size_t)blockIdx.x * 64 * K);
        float4* Al = reinterpret_cast<float4*>(a_lds);
        constexpr int NV = (64 * K) / (4 * 256);
        #pragma unroll
        for (int i = 0; i < NV; ++i) Al[t + i * 256] = Ag[t + i * 256];
    }
    __syncthreads();
    int cq = (t & 31) << 2;
    int rg = t >> 5;
    float4 acc[8];
    #pragma unroll
    for (int r = 0; r < 8; ++r) acc[r] = make_float4(0.f, 0.f, 0.f, 0.f);
    #pragma unroll 2
    for (int k = 0; k < K; k += 4) {
        float4 w0 = *reinterpret_cast<const float4*>(&Wt[(k + 0) * EMB + cq]);
        float4 w1 = *reinterpret_cast<const float4*>(&Wt[(k + 1) * EMB + cq]);
        float4 w2 = *reinterpret_cast<const float4*>(&Wt[(k + 2) * EMB + cq]);
        float4 w3 = *reinterpret_cast<const float4*>(&Wt[(k + 3) * EMB + cq]);
        #pragma unroll
        for (int r = 0; r < 8; ++r) {
            float4 a = *reinterpret_cast<const float4*>(&a_lds[(rg * 8 + r) * K + k]);
            acc[r].x = fmaf(a.x, w0.x, fmaf(a.y, w1.x, fmaf(a.z, w2.x, fmaf(a.w, w3.x, acc[r].x))));
            acc[r].y = fmaf(a.x, w0.y, fmaf(a.y, w1.y, fmaf(a.z, w2.y, fmaf(a.w, w3.y, acc[r].y))));
            acc[r].z = fmaf(a.x, w0.z, fmaf(a.y, w1.z, fmaf(a.z, w2.z, fmaf(a.w, w3.z, acc[r].z))));
            acc[r].w = fmaf(a.x, w0.w, fmaf(a.y, w1.w, fmaf(a.z, w2.w, fmaf(a.w, w3.w, acc[r].w))));
        }
    }
    int row0 = blockIdx.x * 64 + rg * 8;
    #pragma unroll
    for (int r = 0; r < 8; ++r) {
        int row = row0 + r;
        if (row < N_NODES) {
            *reinterpret_cast<float4*>(&out[(size_t)row * EMB + cq]) = acc[r];
        }
    }
}

// ---------------- conv2 gather, both halves in one launch, two 128B epochs per half ----------------
// 32 nodes/block, 8 lanes/node; blocks [0,GROB) = half 0, [GROB,2*GROB) = half 1
__global__ void k_gro(const float4* __restrict__ t2, const int* __restrict__ csr_row,
                      const int* __restrict__ off, const float* __restrict__ dinv,
                      const float* __restrict__ bias, const int* __restrict__ batch,
                      float* __restrict__ gsum) {
    __shared__ __align__(16) float hb[32][64];
    __shared__ int bg[32];
    int t = threadIdx.x;
    int bid = blockIdx.x;
    int half = (bid >= GROB) ? 1 : 0;
    int n0 = (half ? bid - GROB : bid) * 32;
    int local = t >> 3;               // 0..31
    int c4l = t & 7;
    int n = n0 + local;
    if (t < 32) bg[t] = (n0 + t < N_NODES) ? batch[n0 + t] : -1;
    int s = 0, e = 0;
    float dn = 0.f;
    bool valid = (n < N_NODES);
    if (valid) { s = off[n]; e = off[n + 1]; dn = dinv[n]; }
    #pragma unroll
    for (int g = 0; g < 2; ++g) {
        int cidx = half * 16 + g * 8 + c4l;
        float4 acc = make_float4(0.f, 0.f, 0.f, 0.f);
        if (valid) {
            acc = t2[(size_t)n * 32 + cidx];      // self term
            int i = s;
            for (; i + 8 <= e; i += 8) {
                int r0 = csr_row[i + 0], r1 = csr_row[i + 1], r2 = csr_row[i + 2], r3 = csr_row[i + 3];
                int r4 = csr_row[i + 4], r5 = csr_row[i + 5], r6 = csr_row[i + 6], r7 = csr_row[i + 7];
                float4 a0 = t2[(size_t)r0 * 32 + cidx], a1 = t2[(size_t)r1 * 32 + cidx];
                float4 a2 = t2[(size_t)r2 * 32 + cidx], a3 = t2[(size_t)r3 * 32 + cidx];
                float4 a4 = t2[(size_t)r4 * 32 + cidx], a5 = t2[(size_t)r5 * 32 + cidx];
                float4 a6 = t2[(size_t)r6 * 32 + cidx], a7 = t2[(size_t)r7 * 32 + cidx];
                f4add(a0, a1); f4add(a2, a3); f4add(a4, a5); f4add(a6, a7);
                f4add(a0, a2); f4add(a4, a6);
                f4add(a0, a4);
                f4add(acc, a0);
            }
            for (; i < e; ++i) {
                float4 a = t2[(size_t)csr_row[i] * 32 + cidx];
                f4add(acc, a);
            }
            float4 b = reinterpret_cast<const float4*>(bias)[cidx];
            acc.x = fmaxf(fmaf(acc.x, dn, b.x), 0.f);
            acc.y = fmaxf(fmaf(acc.y, dn, b.y), 0.f);
            acc.z = fmaxf(fmaf(acc.z, dn, b.z), 0.f);
            acc.w = fmaxf(fmaf(acc.w, dn, b.w), 0.f);
        }
        *reinterpret_cast<float4*>(&hb[local][(g * 8 + c4l) * 4]) = acc;
    }
    __syncthreads();
    {   // readout: ch = t&63 within half, quarter q scans 8 rows
        int ch = t & 63, q = t >> 6;
        int j0 = q * 8;
        int g = bg[j0];
        if (g >= 0) {
            float a = 0.f;
            #pragma unroll
            for (int j = j0; j < j0 + 8; ++j) {
                int gj = bg[j];
                if (gj < 0) break;
                if (gj != g) { atomicAdd(&gsum[g * EMB + half * 64 + ch], a); a = 0.f; g = gj; }
                a += hb[j][ch];
            }
            atomicAdd(&gsum[g * EMB + half * 64 + ch], a);
        }
    }
}

// ---------------- pair MLP, 16 pairs/block, mean-division fused at load ----------------
__global__ void k_mlp16(const float* __restrict__ gemb, const int* __restrict__ cnt,
                        const int* __restrict__ dd, const int* __restrict__ rankx,
                        const float* __restrict__ w1, const float* __restrict__ b1,
                        const float* __restrict__ w2, const float* __restrict__ b2,
                        float* __restrict__ out) {
    __shared__ __align__(16) float pv[PPB][2 * EMB];
    __shared__ float wpart[4][PPB];
    int p0 = blockIdx.x * PPB;
    int t = threadIdx.x;             // 0..255
    int lane = t & 63, wid = t >> 6;
    #pragma unroll
    for (int j = 0; j < PPB; ++j) {
        int p = p0 + j;
        if (t < EMB) {
            int ga = rankx[dd[p]];
            int ca = cnt[ga];
            float ra = 1.0f / (float)(ca > 1 ? ca : 1);
            pv[j][t] = gemb[ga * EMB + t] * ra;
        } else {
            int gb = rankx[dd[N_PAIRS + p]];
            int cb = cnt[gb];
            float rb = 1.0f / (float)(cb > 1 ? cb : 1);
            pv[j][t] = gemb[gb * EMB + (t - EMB)] * rb;
        }
    }
    __syncthreads();
    float acc[PPB];
    float bv = b1[t];
    #pragma unroll
    for (int j = 0; j < PPB; ++j) acc[j] = bv;
    const float4* wrow = reinterpret_cast<const float4*>(&w1[t * 2 * EMB]);
    for (int k = 0; k < (2 * EMB) / 4; ++k) {
        float4 w = wrow[k];
        #pragma unroll
        for (int j = 0; j < PPB; ++j) {
            const float4 xv = *reinterpret_cast<const float4*>(&pv[j][k * 4]);
            acc[j] = fmaf(xv.x, w.x, fmaf(xv.y, w.y, fmaf(xv.z, w.z, fmaf(xv.w, w.w, acc[j]))));
        }
    }
    float w2t = w2[t];
    float contrib[PPB];
    #pragma unroll
    for (int j = 0; j < PPB; ++j) contrib[j] = fmaxf(acc[j], 0.f) * w2t;
    #pragma unroll
    for (int off = 32; off > 0; off >>= 1) {
        #pragma unroll
        for (int j = 0; j < PPB; ++j) contrib[j] += __shfl_down(contrib[j], off, 64);
    }
    if (lane == 0) {
        #pragma unroll
        for (int j = 0; j < PPB; ++j) wpart[wid][j] = contrib[j];
    }
    __syncthreads();
    if (t < PPB) {
        out[p0 + t] = wpart[0][t] + wpart[1][t] + wpart[2][t] + wpart[3][t] + b2[0];
    }
}

extern "C" void kernel_launch(void* const* d_in, const int* in_sizes, int n_in,
                              void* d_out, int out_size, void* d_ws, size_t ws_size,
                              hipStream_t stream) {
    const float* x        = (const float*)d_in[0];
    const int*   ei       = (const int*)d_in[1];      // [2, E]
    const int*   batch    = (const int*)d_in[2];
    const int*   dd       = (const int*)d_in[3];      // [2, P]
    const float* conv1_w  = (const float*)d_in[4];
    const float* conv1_b  = (const float*)d_in[5];
    const float* conv2_w  = (const float*)d_in[6];
    const float* conv2_b  = (const float*)d_in[7];
    const float* reg1_w   = (const float*)d_in[8];
    const float* reg1_b   = (const float*)d_in[9];
    const float* reg2_w   = (const float*)d_in[10];
    const float* reg2_b   = (const float*)d_in[11];
    float* outp = (float*)d_out;

    const int* ei_row = ei;
    const int* ei_col = ei + N_EDGES;

    // ---- workspace layout ----
    char* ws = (char*)d_ws;
    size_t o = 0;
    auto alloc = [&](size_t bytes) -> void* {
        void* p = ws + o;
        o = (o + bytes + 255) & ~(size_t)255;
        return p;
    };
    size_t zero_start = o;
    int*   deg     = (int*)alloc((size_t)N_NODES * DPAD * 4);   // one 64B line per counter
    int*   cnt     = (int*)alloc(N_GRAPHS * 4);
    size_t zero_bytes = o - zero_start;                          // deg + cnt only
    float* gsum    = (float*)alloc(N_GRAPHS * EMB * 4);          // zeroed inside k_pre
    int*   off     = (int*)alloc((N_NODES + 1) * 4);
    float* dinv    = (float*)alloc(N_NODES * 4);
    int*   part    = (int*)alloc(256 * 4);
    int*   pos_e   = (int*)alloc(N_EDGES * 4);
    int*   csr_row = (int*)alloc(N_EDGES * 4);
    int*   rankx   = (int*)alloc(N_GRAPHS * 4);
    float* Wt1     = (float*)alloc(IN_CH * EMB * 4);
    float* Wt2     = (float*)alloc(EMB * EMB * 4);
    float* h1s     = (float*)alloc((size_t)N_PAD * EMB * 4);
    float* t2      = (float*)alloc((size_t)N_PAD * EMB * 4);
    float* xs      = t2;   // xs (12.8MB) dead before GEMM2 writes t2

    (void)ws_size; (void)in_sizes; (void)n_in; (void)out_size;

    // zero deg+cnt (~3.2 MB)
    {
        int n4 = (int)(zero_bytes / 16);
        k_zero<<<(n4 + 255) / 256, 256, 0, stream>>>((float4*)(ws + zero_start), n4);
    }

    // pre: deg atomics + pos_e + cnt + transposes + digitize + gsum zero
    k_pre<<<N_EDGES / 256 + 1 + 16, 256, 0, stream>>>(ei_col, batch, conv1_w, conv2_w,
                                                      deg, pos_e, cnt, Wt1, Wt2,
                                                      dd, rankx, (float4*)gsum);
    {
        int nb = (N_NODES + 255) / 256;   // 196
        k_scan1<<<nb, 256, 0, stream>>>(deg, part, N_NODES);
        k_scan3d<<<nb, 256, 0, stream>>>(deg, part, off, dinv);
    }
    k_fill_scale<<<(N_EDGES + N_NODES * (IN_CH / 4)) / 256, 256, 0, stream>>>(
        ei_row, ei_col, pos_e, off, csr_row, (const float4*)x, dinv, (float4*)xs);

    // conv1 fused: gather(64ch, 2 channel epochs)->LDS->GEMM1(+bias,relu,dinv postscale)
    k_conv1f<<<N_PAD / 32, 256, 0, stream>>>(
        (const float4*)xs, csr_row, off, dinv, Wt1, conv1_b, h1s);

    // conv2: GEMM (LDS-A), then single-launch gather (2 halves x 2 epochs) + readout
    k_gemmv5<EMB><<<N_PAD / 64, 256, 0, stream>>>(h1s, Wt2, t2);
    k_gro<<<2 * GROB, 256, 0, stream>>>(
        (const float4*)t2, csr_row, off, dinv, conv2_b, batch, gsum);

    // pair MLP (mean division fused)
    k_mlp16<<<N_PAIRS / PPB, 256, 0, stream>>>(gsum, cnt, dd, rankx,
                                               reg1_w, reg1_b, reg2_w, reg2_b, outp);
}